// Round 2
// baseline (541.888 us; speedup 1.0000x reference)
//
#include <hip/hip_runtime.h>
#include <math.h>

// EulerAttention: B=2, S=4096, D=1024.
// Pipeline: [K0] split fp32 -> (hi,lo) bf16 for x and stacked W  (elementwise)
//           [K1] proj: deep-pipelined bf16 NT GEMM with STACKED K=3072
//                (segments: Xhi*Whi, Xhi*Wlo, Xlo*Whi), epilogue bias +
//                HW-trig sincos -> Qf/Kf bf16 features, V -> Vt
//           [K2] 256^2-tile deep-pipelined bf16 NT GEMM (z=2): sim = Qf @ Kf^T
//           [K3] row softmax: fp32 sim -> bf16 P in place (row stride 8192)
//           [K4] same 256^2 core, split-K x2 -> separate fp32 partials
//           [K5] float4 reduce -> out
// ws (two-sim mode, 218MB): [sim0 67MB (aliases split bufs)][Qf 33.5][Kf 33.5]
//   [Vt 16.8][sim1 67]. Partials alias Qf+Kf after K2. Fallback <218MB:
//   sequential per-batch, atomic split-K k4 (old 128^2 core).
//
// Precision notes (load-bearing):
//  - sim ~ 640 +- ~15. sim MUST be fp32 (R1 failure).
//  - Q/K need near-fp32: inv_wl[0]~163 amplifies Q error. 3-term split-bf16.
//    fp32 accumulator -> segment-major term order (vs interleaved) is fine.
//  - R3 failure: libm sincosf -> scratch spill. Trig MUST be inline v_sin/v_cos.
// Perf notes:
//  - R10: k2/k4 -> 256^2 tile, 8 waves, BK=32, 4-deep circular LDS (128KB),
//    counted vmcnt (never drain), setprio. 645->508us; k2/k4 left top-5.
//  - R11 (this): proj -> same T3+T4+T5 structure. 128x256 tile, BK=32,
//    4-deep (96KB), stacked-K segments, grid 12x64 = 768 = 3 perfect waves,
//    3 loads/wave/stage uniform -> vmcnt(6) steady state. Old proj was 185us,
//    MfmaUtil 37%, 2.5e7 bank conflicts (padded reg-staged LDS writes).

typedef __attribute__((ext_vector_type(8))) short bf16x8;
typedef __attribute__((ext_vector_type(4))) float f32x4;

__device__ __forceinline__ float b2f(unsigned short h) {
    union { unsigned int u; float f; } v; v.u = ((unsigned int)h) << 16; return v.f;
}
__device__ __forceinline__ unsigned short f2b(float f) {
    union { float f; unsigned int u; } v; v.f = f;
    unsigned int r = v.u + 0x7fffu + ((v.u >> 16) & 1u);
    return (unsigned short)(r >> 16);
}

// Async global->LDS 16B per lane. LDS dest = wave-uniform base + lane*16.
__device__ __forceinline__ void async_load16(const unsigned short* g, unsigned short* l) {
    __builtin_amdgcn_global_load_lds(
        (const __attribute__((address_space(1))) unsigned int*)g,
        (__attribute__((address_space(3))) unsigned int*)l, 16, 0, 0);
}

// Branch-free sin/cos of th (radians). HW v_sin/v_cos take REVOLUTIONS.
__device__ __forceinline__ void fast_sincos(float th, float* sn, float* cs) {
    float rev = th * 0.15915494309189535f;
    float fr  = rev - floorf(rev);
    float s, c;
    asm("v_sin_f32 %0, %1" : "=v"(s) : "v"(fr));
    asm("v_cos_f32 %0, %1" : "=v"(c) : "v"(fr));
    *sn = s; *cs = c;
}

// ---------------- K0: fp32 -> (hi, lo) bf16 split ----------------
__global__ __launch_bounds__(256) void split_kernel(
    const float* __restrict__ src,
    unsigned short* __restrict__ hi, unsigned short* __restrict__ lo, int n4)
{
    int i = blockIdx.x * 256 + threadIdx.x;
    if (i >= n4) return;
    float4 v = ((const float4*)src)[i];
    float f[4] = { v.x, v.y, v.z, v.w };
    unsigned short h[4], l[4];
#pragma unroll
    for (int j = 0; j < 4; j++) {
        h[j] = f2b(f[j]);
        float r = f[j] - b2f(h[j]);
        l[j] = f2b(r);
    }
    uint2 ho, lv;
    ho.x = (unsigned int)h[0] | ((unsigned int)h[1] << 16);
    ho.y = (unsigned int)h[2] | ((unsigned int)h[3] << 16);
    lv.x = (unsigned int)l[0] | ((unsigned int)l[1] << 16);
    lv.y = (unsigned int)l[2] | ((unsigned int)l[3] << 16);
    ((uint2*)hi)[i] = ho;
    ((uint2*)lo)[i] = lv;
}

__global__ __launch_bounds__(256) void split_w_kernel(
    const float* __restrict__ Wq, const float* __restrict__ Wk,
    const float* __restrict__ Wv,
    unsigned short* __restrict__ hi, unsigned short* __restrict__ lo)
{
    const int y = blockIdx.y;
    const float* src = (y == 0) ? Wq : ((y == 1) ? Wk : Wv);
    size_t off4 = (size_t)y * (1024 * 1024 / 4);
    int i = blockIdx.x * 256 + threadIdx.x;
    float4 v = ((const float4*)src)[i];
    float f[4] = { v.x, v.y, v.z, v.w };
    unsigned short h[4], l[4];
#pragma unroll
    for (int j = 0; j < 4; j++) {
        h[j] = f2b(f[j]);
        float r = f[j] - b2f(h[j]);
        l[j] = f2b(r);
    }
    uint2 ho, lv;
    ho.x = (unsigned int)h[0] | ((unsigned int)h[1] << 16);
    ho.y = (unsigned int)h[2] | ((unsigned int)h[3] << 16);
    lv.x = (unsigned int)l[0] | ((unsigned int)l[1] << 16);
    lv.y = (unsigned int)l[2] | ((unsigned int)l[3] << 16);
    ((uint2*)hi)[off4 + i] = ho;
    ((uint2*)lo)[off4 + i] = lv;
}

// ---------------- K1: proj, deep-pipelined stacked-K GEMM ----------------
// C[8192][3072] = [Xhi|Xhi|Xlo](K=3072-stacked) @ [Whi|Wlo|Whi]^T, fp32 acc.
// 128x256 tile, BK=32, 8 waves (2 row x 4 col), per-wave 64x64 acc[4][4].
// LDS: 4-deep circular, buf = kt&3: [A 128x32 | B 256x32] bf16 = 24KB -> 96KB.
// Staging: 24 chunks (A 8 + B 16) of 16 rows x 32k = 1KB, 3 per wave
// (c = wid*3+i), global_load_lds width=16 with cgl swizzle; reads use qx.
// Schedule: prologue STAGE(0..2), vmcnt(6), barrier.
//   iter t: STAGE(t+3) [into buf (t-1)&3]; COMPUTE(t) [12 ds_read_b128 +
//           setprio(1) 16 MFMA setprio(0)]; vmcnt(6); s_barrier.
//   epilogue: C(NT-3) vmcnt(3) bar; C(NT-2) vmcnt(0) bar; C(NT-1).
// Grid (12, 64) = 768 blocks = 3 perfect occupancy waves (1 wg/CU by LDS).
__global__ __launch_bounds__(512, 2) void proj_kernel(
    const unsigned short* __restrict__ Xhi, const unsigned short* __restrict__ Xlo,
    const unsigned short* __restrict__ Whi, const unsigned short* __restrict__ Wlo,
    const float* __restrict__ bq, const float* __restrict__ bk,
    const float* __restrict__ bv, const float* __restrict__ phase,
    unsigned short* __restrict__ Qf, unsigned short* __restrict__ Kf,
    unsigned short* __restrict__ Vt)
{
    const int m0 = blockIdx.y * 128;
    const int n0 = blockIdx.x * 256;

    __shared__ unsigned short lds[4 * 12288];   // 96 KiB

    const int tid  = threadIdx.x;           // 0..511
    const int lane = tid & 63;
    const int wid  = tid >> 6;              // 0..7
    const int wm   = wid >> 2;              // 0..1: 64-row half
    const int wn   = wid & 3;               // 0..3: 64-col quarter
    const int l15  = lane & 15, q = lane >> 4;
    const int lrow = lane >> 2;
    const int cgl  = (lane & 3) ^ ((lane >> 3) & 3);
    const int qx   = q ^ ((l15 >> 1) & 3);

    f32x4 acc[4][4];
#pragma unroll
    for (int a = 0; a < 4; a++)
#pragma unroll
        for (int b = 0; b < 4; b++) acc[a][b] = (f32x4){0.f, 0.f, 0.f, 0.f};

    const int NT = 96;                      // 3 segments x 32 K-tiles

    auto STAGE = [&](int kt) {
        const unsigned short* Asrc = (kt < 64) ? Xhi : Xlo;   // seg 0,1 / 2
        const unsigned short* Bsrc = ((kt >> 5) == 1) ? Wlo : Whi;
        const int kg = (kt & 31) * 32;
        unsigned short* buf = &lds[(kt & 3) * 12288];
#pragma unroll
        for (int i = 0; i < 3; i++) {
            const int c = wid * 3 + i;      // 0..23
            if (c < 8) {
                async_load16(&Asrc[(size_t)(m0 + c * 16 + lrow) * 1024 + kg + cgl * 8],
                             &buf[c * 512]);
            } else {
                const int cb = c - 8;       // 0..15
                async_load16(&Bsrc[(size_t)(n0 + cb * 16 + lrow) * 1024 + kg + cgl * 8],
                             &buf[4096 + cb * 512]);
            }
        }
    };

    auto COMPUTE = [&](int kt) {
        const unsigned short* buf = &lds[(kt & 3) * 12288];
        bf16x8 af[4], bfr[4];
#pragma unroll
        for (int mt = 0; mt < 4; mt++) {
            const int ar = wm * 64 + mt * 16 + l15;
            af[mt] = *(const bf16x8*)&buf[(ar * 4 + qx) * 8];
        }
#pragma unroll
        for (int nt = 0; nt < 4; nt++) {
            const int br = wn * 64 + nt * 16 + l15;
            bfr[nt] = *(const bf16x8*)&buf[4096 + (br * 4 + qx) * 8];
        }
        __builtin_amdgcn_s_setprio(1);
#pragma unroll
        for (int mt = 0; mt < 4; mt++)
#pragma unroll
            for (int nt = 0; nt < 4; nt++)
                acc[mt][nt] = __builtin_amdgcn_mfma_f32_16x16x32_bf16(
                    af[mt], bfr[nt], acc[mt][nt], 0, 0, 0);
        __builtin_amdgcn_s_setprio(0);
    };

    STAGE(0); STAGE(1); STAGE(2);
    asm volatile("s_waitcnt vmcnt(6)" ::: "memory");
    asm volatile("s_barrier" ::: "memory");

    for (int t = 0; t < NT - 3; ++t) {
        STAGE(t + 3);
        COMPUTE(t);
        asm volatile("s_waitcnt vmcnt(6)" ::: "memory");
        asm volatile("s_barrier" ::: "memory");
    }
    COMPUTE(NT - 3);
    asm volatile("s_waitcnt vmcnt(3)" ::: "memory");
    asm volatile("s_barrier" ::: "memory");
    COMPUTE(NT - 2);
    asm volatile("s_waitcnt vmcnt(0)" ::: "memory");
    asm volatile("s_barrier" ::: "memory");
    COMPUTE(NT - 1);

    const float w0 = (float)(2.0 * M_PI / 1024.0);

#pragma unroll
    for (int nt = 0; nt < 4; nt++) {
        const int n  = n0 + wn * 64 + nt * 16 + l15;
        const int f  = n & 1023;
        const int zz = n >> 10;             // 0=Q,1=K,2=V; uniform per 16-col grp
        const float bsv = (zz == 0) ? bq[f] : ((zz == 1) ? bk[f] : bv[f]);
        const float wl  = (float)(f + 1) * w0;
        const float inv = 1.0f / (wl + 1e-8f);
        const float phv = phase[f];
        unsigned short* dst = (zz == 0) ? Qf : Kf;
#pragma unroll
        for (int mt = 0; mt < 4; mt++) {
#pragma unroll
            for (int r = 0; r < 4; r++) {
                const int m  = m0 + wm * 64 + mt * 16 + q * 4 + r;
                const int bb = m >> 12;
                const int s  = m & 4095;
                float val = acc[mt][nt][r] + bsv;
                if (zz == 2) {
                    Vt[((size_t)bb * 1024 + f) * 4096 + s] = f2b(val);
                } else {
                    float th = fmaf(val, inv, phv);
                    float sn, cs;
                    fast_sincos(th, &sn, &cs);
                    size_t base = ((size_t)bb * 4096 + s) * 2048;
                    dst[base + f]        = f2b(cs);
                    dst[base + 1024 + f] = f2b(sn);
                }
            }
        }
    }
}

// ---------------- old 128^2 core: kept ONLY for atomic fallback ------------
template <int LDA, int LDB, int LDC, int KLEN, int SLICES, bool ATOMIC, bool PARTIAL>
__device__ __forceinline__ void gemm_core(
    const unsigned short* __restrict__ A,
    const unsigned short* __restrict__ Bm,
    float* __restrict__ C, size_t sA, size_t sB, size_t sC)
{
    const int bz = blockIdx.z;
    const int batch = bz / SLICES;
    const int slice = bz % SLICES;
    A  += (size_t)batch * sA;
    Bm += (size_t)batch * sB;
    C  += PARTIAL ? (size_t)bz * sC : (size_t)batch * sC;
    const int koff = slice * KLEN;

    const int m0 = blockIdx.y * 128;
    const int n0 = blockIdx.x * 128;

    __shared__ unsigned short As[128 * 32];
    __shared__ unsigned short Bs[128 * 32];

    const int tid  = threadIdx.x;
    const int lane = tid & 63;
    const int w    = tid >> 6;
    const int wr   = w >> 1, wc = w & 1;
    const int l15  = lane & 15, q = lane >> 4;
    const int lrow = lane >> 2;
    const int cgl  = (lane & 3) ^ ((lane >> 3) & 3);
    const int qx   = q ^ ((l15 >> 1) & 3);

    f32x4 acc[4][4];
#pragma unroll
    for (int a = 0; a < 4; a++)
#pragma unroll
        for (int b = 0; b < 4; b++) acc[a][b] = (f32x4){0.f, 0.f, 0.f, 0.f};

    for (int k0 = 0; k0 < KLEN; k0 += 32) {
        int kg = koff + k0;
#pragma unroll
        for (int i = 0; i < 2; i++) {
            int chunk = w * 2 + i;
            async_load16(&A[(size_t)(m0 + chunk * 16 + lrow) * LDA + kg + cgl * 8],
                         &As[chunk * 512]);
            async_load16(&Bm[(size_t)(n0 + chunk * 16 + lrow) * LDB + kg + cgl * 8],
                         &Bs[chunk * 512]);
        }
        __syncthreads();
        bf16x8 af[4], bfr[4];
#pragma unroll
        for (int mt = 0; mt < 4; mt++) {
            int ar = wr * 64 + mt * 16 + l15;
            af[mt] = *(const bf16x8*)&As[(ar * 4 + qx) * 8];
        }
#pragma unroll
        for (int nt = 0; nt < 4; nt++) {
            int br = wc * 64 + nt * 16 + l15;
            bfr[nt] = *(const bf16x8*)&Bs[(br * 4 + qx) * 8];
        }
#pragma unroll
        for (int mt = 0; mt < 4; mt++)
#pragma unroll
            for (int nt = 0; nt < 4; nt++)
                acc[mt][nt] = __builtin_amdgcn_mfma_f32_16x16x32_bf16(
                    af[mt], bfr[nt], acc[mt][nt], 0, 0, 0);
        __syncthreads();
    }

#pragma unroll
    for (int mt = 0; mt < 4; mt++) {
#pragma unroll
        for (int nt = 0; nt < 4; nt++) {
            int n = n0 + wc * 64 + nt * 16 + l15;
#pragma unroll
            for (int r = 0; r < 4; r++) {
                int m = m0 + wr * 64 + mt * 16 + q * 4 + r;
                float* p = &C[(size_t)m * LDC + n];
                if (ATOMIC)
                    __hip_atomic_fetch_add(p, acc[mt][nt][r],
                                           __ATOMIC_RELAXED, __HIP_MEMORY_SCOPE_AGENT);
                else
                    *p = acc[mt][nt][r];
            }
        }
    }
}

// k4 fallback path (one sim): atomic split-K x4 within one batch.
__global__ __launch_bounds__(256) void k4_gemm_atomic(
    const unsigned short* __restrict__ A, const unsigned short* __restrict__ Bm,
    float* __restrict__ C, size_t sA, size_t sB, size_t sC)
{
    gemm_core<8192, 4096, 1024, 1024, 4, true, false>(A, Bm, C, sA, sB, sC);
}

// ---------------- 256^2 deep-pipelined core (T3+T4+T5) ---------------------
// 512 threads = 8 waves (2 row-halves x 4 col-quarters), per-wave C = 128x64
// (acc[8][4]), BK=32, mfma_f32_16x16x32_bf16.
// LDS: 4-deep circular pipeline of K-tiles, buffer j = kt&3:
//   [A 256x32 bf16 | B 256x32 bf16] = 32KB; 4 bufs = 128KB -> 1 wg/CU.
// Schedule: counted vmcnt(8) in-loop (2 stages in flight behind the one
// landing), epilogue 8->4->0. No __syncthreads -> no compiler drain.
template <int LDA, int LDB, int LDC, int KLEN, int SLICES, bool PARTIAL>
__device__ __forceinline__ void gemm256_core(
    const unsigned short* __restrict__ A,
    const unsigned short* __restrict__ Bm,
    float* __restrict__ C, size_t sA, size_t sB, size_t sC)
{
    const int bz = blockIdx.z;
    const int batch = bz / SLICES;
    const int slice = bz % SLICES;
    A  += (size_t)batch * sA;
    Bm += (size_t)batch * sB;
    C  += PARTIAL ? (size_t)bz * sC : (size_t)batch * sC;
    const int koff = slice * KLEN;

    const int m0 = blockIdx.y * 256;
    const int n0 = blockIdx.x * 256;

    __shared__ unsigned short lds[4 * 16384];   // 128 KiB

    const int tid  = threadIdx.x;           // 0..511
    const int lane = tid & 63;
    const int wid  = tid >> 6;              // 0..7
    const int wm   = wid >> 2;              // 0..1: 128-row half
    const int wn   = wid & 3;               // 0..3: 64-col quarter
    const int l15  = lane & 15, q = lane >> 4;
    const int lrow = lane >> 2;
    const int cgl  = (lane & 3) ^ ((lane >> 3) & 3);
    const int qx   = q ^ ((l15 >> 1) & 3);

    f32x4 acc[8][4];
#pragma unroll
    for (int a = 0; a < 8; a++)
#pragma unroll
        for (int b = 0; b < 4; b++) acc[a][b] = (f32x4){0.f, 0.f, 0.f, 0.f};

    const int NT = KLEN / 32;               // 64 K-tiles

    auto STAGE = [&](int kt) {
        const int kg = koff + kt * 32;
        unsigned short* buf = &lds[(kt & 3) * 16384];
#pragma unroll
        for (int i = 0; i < 2; i++) {
            const int chunk = wid * 2 + i;  // 2 of 16 A-chunks + 2 of 16 B-chunks
            async_load16(&A[(size_t)(m0 + chunk * 16 + lrow) * LDA + kg + cgl * 8],
                         &buf[chunk * 512]);
            async_load16(&Bm[(size_t)(n0 + chunk * 16 + lrow) * LDB + kg + cgl * 8],
                         &buf[8192 + chunk * 512]);
        }
    };

    auto COMPUTE = [&](int kt) {
        const unsigned short* buf = &lds[(kt & 3) * 16384];
        bf16x8 af[8], bfr[4];
#pragma unroll
        for (int mt = 0; mt < 8; mt++) {
            const int ar = wm * 128 + mt * 16 + l15;
            af[mt] = *(const bf16x8*)&buf[(ar * 4 + qx) * 8];
        }
#pragma unroll
        for (int nt = 0; nt < 4; nt++) {
            const int br = wn * 64 + nt * 16 + l15;
            bfr[nt] = *(const bf16x8*)&buf[8192 + (br * 4 + qx) * 8];
        }
        __builtin_amdgcn_s_setprio(1);
#pragma unroll
        for (int mt = 0; mt < 8; mt++)
#pragma unroll
            for (int nt = 0; nt < 4; nt++)
                acc[mt][nt] = __builtin_amdgcn_mfma_f32_16x16x32_bf16(
                    af[mt], bfr[nt], acc[mt][nt], 0, 0, 0);
        __builtin_amdgcn_s_setprio(0);
    };

    STAGE(0); STAGE(1); STAGE(2);
    asm volatile("s_waitcnt vmcnt(8)" ::: "memory");
    asm volatile("s_barrier" ::: "memory");

    for (int t = 0; t < NT - 3; ++t) {
        STAGE(t + 3);
        COMPUTE(t);
        asm volatile("s_waitcnt vmcnt(8)" ::: "memory");
        asm volatile("s_barrier" ::: "memory");
    }
    COMPUTE(NT - 3);
    asm volatile("s_waitcnt vmcnt(4)" ::: "memory");
    asm volatile("s_barrier" ::: "memory");
    COMPUTE(NT - 2);
    asm volatile("s_waitcnt vmcnt(0)" ::: "memory");
    asm volatile("s_barrier" ::: "memory");
    COMPUTE(NT - 1);

#pragma unroll
    for (int mt = 0; mt < 8; mt++) {
#pragma unroll
        for (int nt = 0; nt < 4; nt++) {
            const int n = n0 + wn * 64 + nt * 16 + l15;
#pragma unroll
            for (int r = 0; r < 4; r++) {
                const int m = m0 + wm * 128 + mt * 16 + q * 4 + r;
                C[(size_t)m * LDC + n] = acc[mt][nt][r];
            }
        }
    }
}

__global__ __launch_bounds__(512, 2) void k2_gemm256(
    const unsigned short* __restrict__ A, const unsigned short* __restrict__ Bm,
    float* __restrict__ C, size_t sA, size_t sB, size_t sC)
{
    gemm256_core<2048, 2048, 4096, 2048, 1, false>(A, Bm, C, sA, sB, sC);
}

__global__ __launch_bounds__(512, 2) void k4_gemm256(
    const unsigned short* __restrict__ A, const unsigned short* __restrict__ Bm,
    float* __restrict__ C, size_t sA, size_t sB, size_t sC)
{
    gemm256_core<8192, 4096, 1024, 2048, 2, true>(A, Bm, C, sA, sB, sC);
}

// ---------------- K5: reduce partials -> out ----------------
__global__ __launch_bounds__(256) void reduce_kernel(
    const float* __restrict__ part, float* __restrict__ out)
{
    int j4 = blockIdx.x * 256 + threadIdx.x;      // float4 index, < 2*1048576
    int b  = j4 >> 20;
    int jj = j4 & 1048575;
    const float4* p0 = (const float4*)(part + (size_t)(b * 2 + 0) * 4194304);
    const float4* p1 = (const float4*)(part + (size_t)(b * 2 + 1) * 4194304);
    float4 a = p0[jj], c = p1[jj];
    float4 r; r.x = a.x + c.x; r.y = a.y + c.y; r.z = a.z + c.z; r.w = a.w + c.w;
    ((float4*)out)[j4] = r;
}

// ---------------- K3: row softmax, fp32 sim -> bf16 P in place -------------
__global__ __launch_bounds__(256) void softmax_kernel(float* __restrict__ simbase,
                                                      size_t batchStride)
{
    const int row = blockIdx.x;
    float* sim = simbase + (size_t)(row >> 12) * batchStride;
    const int r = row & 4095;
    const float* pin = sim + (size_t)r * 4096;
    unsigned short* pout = (unsigned short*)sim + (size_t)r * 8192;
    const int tid = threadIdx.x;

    float v[16];
#pragma unroll
    for (int i = 0; i < 4; i++) {
        float4 d = ((const float4*)pin)[tid * 4 + i];
        v[4 * i + 0] = d.x * 0.03125f;
        v[4 * i + 1] = d.y * 0.03125f;
        v[4 * i + 2] = d.z * 0.03125f;
        v[4 * i + 3] = d.w * 0.03125f;
    }

    float m = v[0];
#pragma unroll
    for (int i = 1; i < 16; i++) m = fmaxf(m, v[i]);
    for (int o = 32; o > 0; o >>= 1) m = fmaxf(m, __shfl_xor(m, o));
    __shared__ float red[4];
    if ((tid & 63) == 0) red[tid >> 6] = m;
    __syncthreads();
    m = fmaxf(fmaxf(red[0], red[1]), fmaxf(red[2], red[3]));
    __syncthreads();

    float e[16];
    float s = 0.f;
#pragma unroll
    for (int i = 0; i < 16; i++) { e[i] = expf(v[i] - m); s += e[i]; }
    for (int o = 32; o > 0; o >>= 1) s += __shfl_xor(s, o);
    if ((tid & 63) == 0) red[tid >> 6] = s;
    __syncthreads();
    float l = (red[0] + red[1]) + (red[2] + red[3]);
    float inv = 1.0f / l;

#pragma unroll
    for (int c = 0; c < 2; c++) {
        unsigned int wds[4];
#pragma unroll
        for (int i = 0; i < 4; i++) {
            unsigned int lo = f2b(e[c * 8 + 2 * i] * inv);
            unsigned int hi = f2b(e[c * 8 + 2 * i + 1] * inv);
            wds[i] = lo | (hi << 16);
        }
        uint4 o4; o4.x = wds[0]; o4.y = wds[1]; o4.z = wds[2]; o4.w = wds[3];
        ((uint4*)pout)[tid * 2 + c] = o4;
    }
}

extern "C" void kernel_launch(void* const* d_in, const int* in_sizes, int n_in,
                              void* d_out, int out_size, void* d_ws, size_t ws_size,
                              hipStream_t stream)
{
    const float* x  = (const float*)d_in[0];
    const float* Wq = (const float*)d_in[1];
    const float* bq = (const float*)d_in[2];
    const float* Wk = (const float*)d_in[3];
    const float* bk = (const float*)d_in[4];
    const float* Wv = (const float*)d_in[5];
    const float* bv = (const float*)d_in[6];
    const float* ph = (const float*)d_in[7];

    char* ws = (char*)d_ws;
    const size_t SIMB = (size_t)4096 * 4096 * 4;                  // 67.1MB
    unsigned short* Xhi = (unsigned short*)ws;                    // aliases sim0
    unsigned short* Xlo = Xhi + (size_t)8192 * 1024;
    unsigned short* Whi = Xlo + (size_t)8192 * 1024;
    unsigned short* Wlo = Whi + (size_t)3072 * 1024;
    float*          sim0 = (float*)ws;
    unsigned short* Qf = (unsigned short*)(ws + SIMB);            // [2][4096][2048]
    unsigned short* Kf = Qf + (size_t)2 * 4096 * 2048;            // [2][4096][2048]
    unsigned short* Vt = Kf + (size_t)2 * 4096 * 2048;            // [2][1024][4096]
    float*          sim1 = (float*)(ws + SIMB + (size_t)83886080); // after Vt
    float*          part = (float*)(ws + SIMB);                   // aliases Qf+Kf (dead after k2)
    const bool twoSim = ws_size >= (size_t)218103808;

    split_kernel<<<8192, 256, 0, stream>>>(x, Xhi, Xlo, 8192 * 1024 / 4);
    split_w_kernel<<<dim3(1024, 3), 256, 0, stream>>>(Wq, Wk, Wv, Whi, Wlo);
    proj_kernel<<<dim3(12, 64), 512, 0, stream>>>(Xhi, Xlo, Whi, Wlo,
                                                  bq, bk, bv, ph, Qf, Kf, Vt);

    const size_t sQK = (size_t)4096 * 2048;    // Qf/Kf batch stride (shorts)
    const size_t sV  = (size_t)1024 * 4096;    // Vt batch stride (shorts)
    const size_t sO  = (size_t)4096 * 1024;    // out / partial stride (floats)

    if (twoSim) {
        const size_t sSim = (size_t)(sim1 - sim0);   // floats between sims
        k2_gemm256<<<dim3(16, 16, 2), 512, 0, stream>>>(Qf, Kf, sim0, sQK, sQK, sSim);
        softmax_kernel<<<8192, 256, 0, stream>>>(sim0, sSim);
        // out partials: z = batch*2 + slice, each slice K=2048 of 4096
        k4_gemm256<<<dim3(4, 16, 4), 512, 0, stream>>>((const unsigned short*)sim0, Vt,
                                                       part, sSim * 2, sV, sO);
        reduce_kernel<<<8192, 256, 0, stream>>>(part, (float*)d_out);
    } else {
        hipMemsetAsync(d_out, 0, (size_t)2 * 4096 * 1024 * sizeof(float), stream);
        for (int b = 0; b < 2; b++) {
            const unsigned short* Qb = Qf + (size_t)b * sQK;
            const unsigned short* Kb = Kf + (size_t)b * sQK;
            const unsigned short* Vb = Vt + (size_t)b * sV;
            float* outb = (float*)d_out + (size_t)b * sO;
            k2_gemm256<<<dim3(16, 16, 1), 512, 0, stream>>>(Qb, Kb, sim0, 0, 0, 0);
            softmax_kernel<<<4096, 256, 0, stream>>>(sim0, 0);
            k4_gemm_atomic<<<dim3(8, 32, 4), 256, 0, stream>>>(
                (const unsigned short*)sim0, Vb, outb, 0, 0, 0);
        }
    }
}

// Round 3
// 511.049 us; speedup vs baseline: 1.0603x; 1.0603x over previous
//
#include <hip/hip_runtime.h>
#include <math.h>

// EulerAttention: B=2, S=4096, D=1024.
// Pipeline: [K0] split fp32 -> (hi,lo) bf16 for x and stacked W  (elementwise)
//           [K1] split-bf16 MFMA GEMM (3-term), M=8192 N=3072 K=1024,
//                epilogue: bias + HW-trig sincos -> Qf/Kf bf16 features, V -> Vt
//           [K2] 256^2-tile sub-phased pipelined bf16 NT GEMM (z=2): sim = Qf@Kf^T
//           [K3] row softmax: fp32 sim -> bf16 P in place (row stride 8192)
//           [K4] same 256^2 core, split-K x2 -> separate fp32 partials
//           [K5] float4 reduce -> out
// ws (two-sim mode, 218MB): [sim0 67MB (aliases split bufs)][Qf 33.5][Kf 33.5]
//   [Vt 16.8][sim1 67]. Partials alias Qf+Kf after K2. Fallback <218MB:
//   sequential per-batch, atomic split-K k4 (old 128^2 core).
//
// Precision notes (load-bearing):
//  - sim ~ 640 +- ~15. sim MUST be fp32 (R1 failure).
//  - Q/K need near-fp32: inv_wl[0]~163 amplifies Q error. 3-term split-bf16.
//  - R3 failure: libm sincosf -> scratch spill. Trig MUST be inline v_sin/v_cos.
// Perf notes:
//  - R4: proj 186us = 831 TF (m97-structure, 2 blk/CU). R11's stacked-K
//    deep-pipe proj REGRESSED to 233us (16-MFMA phases too small, +45% L2
//    traffic) -> REVERTED to this version. Do not re-attempt without BK=64.
//  - R10: k2/k4 256^2 coarse counted-vmcnt: k2 212->~145, k4 165->~95. Phase
//    time ~2500cyc vs ~350cyc work -> m196's "coarse phase-split hurts" regime.
//  - R12 (this): gemm256 -> m201-style SUB-PHASES: per BK=32 K-tile, 2x
//    {ds_reads; stage half; barrier; lgkmcnt(0); setprio(1); 16 MFMA;
//    setprio(0); [vmcnt(8) once/K-tile]; barrier}. Same 4-deep bufs, same
//    swizzle, strictly stronger sync than R10 (no new race surface).

typedef __attribute__((ext_vector_type(8))) short bf16x8;
typedef __attribute__((ext_vector_type(4))) float f32x4;

__device__ __forceinline__ float b2f(unsigned short h) {
    union { unsigned int u; float f; } v; v.u = ((unsigned int)h) << 16; return v.f;
}
__device__ __forceinline__ unsigned short f2b(float f) {
    union { float f; unsigned int u; } v; v.f = f;
    unsigned int r = v.u + 0x7fffu + ((v.u >> 16) & 1u);
    return (unsigned short)(r >> 16);
}

// Async global->LDS 16B per lane. LDS dest = wave-uniform base + lane*16.
__device__ __forceinline__ void async_load16(const unsigned short* g, unsigned short* l) {
    __builtin_amdgcn_global_load_lds(
        (const __attribute__((address_space(1))) unsigned int*)g,
        (__attribute__((address_space(3))) unsigned int*)l, 16, 0, 0);
}

// Branch-free sin/cos of th (radians). HW v_sin/v_cos take REVOLUTIONS.
__device__ __forceinline__ void fast_sincos(float th, float* sn, float* cs) {
    float rev = th * 0.15915494309189535f;
    float fr  = rev - floorf(rev);
    float s, c;
    asm("v_sin_f32 %0, %1" : "=v"(s) : "v"(fr));
    asm("v_cos_f32 %0, %1" : "=v"(c) : "v"(fr));
    *sn = s; *cs = c;
}

// ---------------- K0: fp32 -> (hi, lo) bf16 split ----------------
__global__ __launch_bounds__(256) void split_kernel(
    const float* __restrict__ src,
    unsigned short* __restrict__ hi, unsigned short* __restrict__ lo, int n4)
{
    int i = blockIdx.x * 256 + threadIdx.x;
    if (i >= n4) return;
    float4 v = ((const float4*)src)[i];
    float f[4] = { v.x, v.y, v.z, v.w };
    unsigned short h[4], l[4];
#pragma unroll
    for (int j = 0; j < 4; j++) {
        h[j] = f2b(f[j]);
        float r = f[j] - b2f(h[j]);
        l[j] = f2b(r);
    }
    uint2 ho, lv;
    ho.x = (unsigned int)h[0] | ((unsigned int)h[1] << 16);
    ho.y = (unsigned int)h[2] | ((unsigned int)h[3] << 16);
    lv.x = (unsigned int)l[0] | ((unsigned int)l[1] << 16);
    lv.y = (unsigned int)l[2] | ((unsigned int)l[3] << 16);
    ((uint2*)hi)[i] = ho;
    ((uint2*)lo)[i] = lv;
}

__global__ __launch_bounds__(256) void split_w_kernel(
    const float* __restrict__ Wq, const float* __restrict__ Wk,
    const float* __restrict__ Wv,
    unsigned short* __restrict__ hi, unsigned short* __restrict__ lo)
{
    const int y = blockIdx.y;
    const float* src = (y == 0) ? Wq : ((y == 1) ? Wk : Wv);
    size_t off4 = (size_t)y * (1024 * 1024 / 4);
    int i = blockIdx.x * 256 + threadIdx.x;
    float4 v = ((const float4*)src)[i];
    float f[4] = { v.x, v.y, v.z, v.w };
    unsigned short h[4], l[4];
#pragma unroll
    for (int j = 0; j < 4; j++) {
        h[j] = f2b(f[j]);
        float r = f[j] - b2f(h[j]);
        l[j] = f2b(r);
    }
    uint2 ho, lv;
    ho.x = (unsigned int)h[0] | ((unsigned int)h[1] << 16);
    ho.y = (unsigned int)h[2] | ((unsigned int)h[3] << 16);
    lv.x = (unsigned int)l[0] | ((unsigned int)l[1] << 16);
    lv.y = (unsigned int)l[2] | ((unsigned int)l[3] << 16);
    ((uint2*)hi)[off4 + i] = ho;
    ((uint2*)lo)[off4 + i] = lv;
}

// ---------------- K1: split-bf16 MFMA projection GEMM (R8 version) ---------
__global__ __launch_bounds__(256, 2) void proj_kernel(
    const unsigned short* __restrict__ Xhi, const unsigned short* __restrict__ Xlo,
    const unsigned short* __restrict__ Whi, const unsigned short* __restrict__ Wlo,
    const float* __restrict__ bq, const float* __restrict__ bk,
    const float* __restrict__ bv, const float* __restrict__ phase,
    unsigned short* __restrict__ Qf, unsigned short* __restrict__ Kf,
    unsigned short* __restrict__ Vt)
{
    const int m0 = blockIdx.y * 128;
    const int n0 = blockIdx.x * 128;

    __shared__ unsigned short Ah[128 * 40], Al[128 * 40];
    __shared__ unsigned short Bh[128 * 40], Bl[128 * 40];

    const int tid  = threadIdx.x;
    const int lane = tid & 63;
    const int w    = tid >> 6;
    const int wr   = w >> 1, wc = w & 1;
    const int l15  = lane & 15, q = lane >> 4;

    f32x4 acc[4][4];
#pragma unroll
    for (int a = 0; a < 4; a++)
#pragma unroll
        for (int b = 0; b < 4; b++) acc[a][b] = (f32x4){0.f, 0.f, 0.f, 0.f};

    for (int k0 = 0; k0 < 1024; k0 += 32) {
#pragma unroll
        for (int i = 0; i < 2; i++) {
            int idx = tid + 256 * i;
            int row = idx >> 2;
            int cc  = idx & 3;
            size_t ga = (size_t)(m0 + row) * 1024 + k0 + cc * 8;
            size_t gb = (size_t)(n0 + row) * 1024 + k0 + cc * 8;
            *(uint4*)&Ah[row * 40 + cc * 8] = *(const uint4*)&Xhi[ga];
            *(uint4*)&Al[row * 40 + cc * 8] = *(const uint4*)&Xlo[ga];
            *(uint4*)&Bh[row * 40 + cc * 8] = *(const uint4*)&Whi[gb];
            *(uint4*)&Bl[row * 40 + cc * 8] = *(const uint4*)&Wlo[gb];
        }
        __syncthreads();
        bf16x8 ah[4], al[4];
#pragma unroll
        for (int mt = 0; mt < 4; mt++) {
            int off = (wr * 64 + mt * 16 + l15) * 40 + q * 8;
            ah[mt] = *(const bf16x8*)&Ah[off];
            al[mt] = *(const bf16x8*)&Al[off];
        }
#pragma unroll
        for (int nt = 0; nt < 4; nt++) {
            int off = (wc * 64 + nt * 16 + l15) * 40 + q * 8;
            bf16x8 bh = *(const bf16x8*)&Bh[off];
            bf16x8 bl = *(const bf16x8*)&Bl[off];
#pragma unroll
            for (int mt = 0; mt < 4; mt++) {
                acc[mt][nt] = __builtin_amdgcn_mfma_f32_16x16x32_bf16(
                    ah[mt], bh, acc[mt][nt], 0, 0, 0);
                acc[mt][nt] = __builtin_amdgcn_mfma_f32_16x16x32_bf16(
                    ah[mt], bl, acc[mt][nt], 0, 0, 0);
                acc[mt][nt] = __builtin_amdgcn_mfma_f32_16x16x32_bf16(
                    al[mt], bh, acc[mt][nt], 0, 0, 0);
            }
        }
        __syncthreads();
    }

    const int z = n0 >> 10;                   // 0=Q, 1=K, 2=V
    const float* bias = (z == 0) ? bq : ((z == 1) ? bk : bv);
    const float w0 = (float)(2.0 * M_PI / 1024.0);

#pragma unroll
    for (int mt = 0; mt < 4; mt++) {
#pragma unroll
        for (int nt = 0; nt < 4; nt++) {
            int n = n0 + wc * 64 + nt * 16 + l15;
            int f = n & 1023;
            float bsv = bias[f];
            float wl  = (float)(f + 1) * w0;
            float inv = 1.0f / (wl + 1e-8f);
            float phv = phase[f];
#pragma unroll
            for (int r = 0; r < 4; r++) {
                int m  = m0 + wr * 64 + mt * 16 + q * 4 + r;
                int bb = m >> 12;
                int s  = m & 4095;
                float val = acc[mt][nt][r] + bsv;
                if (z == 2) {
                    Vt[((size_t)bb * 1024 + f) * 4096 + s] = f2b(val);
                } else {
                    float th = fmaf(val, inv, phv);
                    float sn, cs;
                    fast_sincos(th, &sn, &cs);
                    unsigned short* dst = (z == 0) ? Qf : Kf;
                    size_t base = ((size_t)bb * 4096 + s) * 2048;
                    dst[base + f]        = f2b(cs);
                    dst[base + 1024 + f] = f2b(sn);
                }
            }
        }
    }
}

// ---------------- old 128^2 core: kept ONLY for atomic fallback ------------
template <int LDA, int LDB, int LDC, int KLEN, int SLICES, bool ATOMIC, bool PARTIAL>
__device__ __forceinline__ void gemm_core(
    const unsigned short* __restrict__ A,
    const unsigned short* __restrict__ Bm,
    float* __restrict__ C, size_t sA, size_t sB, size_t sC)
{
    const int bz = blockIdx.z;
    const int batch = bz / SLICES;
    const int slice = bz % SLICES;
    A  += (size_t)batch * sA;
    Bm += (size_t)batch * sB;
    C  += PARTIAL ? (size_t)bz * sC : (size_t)batch * sC;
    const int koff = slice * KLEN;

    const int m0 = blockIdx.y * 128;
    const int n0 = blockIdx.x * 128;

    __shared__ unsigned short As[128 * 32];
    __shared__ unsigned short Bs[128 * 32];

    const int tid  = threadIdx.x;
    const int lane = tid & 63;
    const int w    = tid >> 6;
    const int wr   = w >> 1, wc = w & 1;
    const int l15  = lane & 15, q = lane >> 4;
    const int lrow = lane >> 2;
    const int cgl  = (lane & 3) ^ ((lane >> 3) & 3);
    const int qx   = q ^ ((l15 >> 1) & 3);

    f32x4 acc[4][4];
#pragma unroll
    for (int a = 0; a < 4; a++)
#pragma unroll
        for (int b = 0; b < 4; b++) acc[a][b] = (f32x4){0.f, 0.f, 0.f, 0.f};

    for (int k0 = 0; k0 < KLEN; k0 += 32) {
        int kg = koff + k0;
#pragma unroll
        for (int i = 0; i < 2; i++) {
            int chunk = w * 2 + i;
            async_load16(&A[(size_t)(m0 + chunk * 16 + lrow) * LDA + kg + cgl * 8],
                         &As[chunk * 512]);
            async_load16(&Bm[(size_t)(n0 + chunk * 16 + lrow) * LDB + kg + cgl * 8],
                         &Bs[chunk * 512]);
        }
        __syncthreads();
        bf16x8 af[4], bfr[4];
#pragma unroll
        for (int mt = 0; mt < 4; mt++) {
            int ar = wr * 64 + mt * 16 + l15;
            af[mt] = *(const bf16x8*)&As[(ar * 4 + qx) * 8];
        }
#pragma unroll
        for (int nt = 0; nt < 4; nt++) {
            int br = wc * 64 + nt * 16 + l15;
            bfr[nt] = *(const bf16x8*)&Bs[(br * 4 + qx) * 8];
        }
#pragma unroll
        for (int mt = 0; mt < 4; mt++)
#pragma unroll
            for (int nt = 0; nt < 4; nt++)
                acc[mt][nt] = __builtin_amdgcn_mfma_f32_16x16x32_bf16(
                    af[mt], bfr[nt], acc[mt][nt], 0, 0, 0);
        __syncthreads();
    }

#pragma unroll
    for (int mt = 0; mt < 4; mt++) {
#pragma unroll
        for (int nt = 0; nt < 4; nt++) {
            int n = n0 + wc * 64 + nt * 16 + l15;
#pragma unroll
            for (int r = 0; r < 4; r++) {
                int m = m0 + wr * 64 + mt * 16 + q * 4 + r;
                float* p = &C[(size_t)m * LDC + n];
                if (ATOMIC)
                    __hip_atomic_fetch_add(p, acc[mt][nt][r],
                                           __ATOMIC_RELAXED, __HIP_MEMORY_SCOPE_AGENT);
                else
                    *p = acc[mt][nt][r];
            }
        }
    }
}

// k4 fallback path (one sim): atomic split-K x4 within one batch.
__global__ __launch_bounds__(256) void k4_gemm_atomic(
    const unsigned short* __restrict__ A, const unsigned short* __restrict__ Bm,
    float* __restrict__ C, size_t sA, size_t sB, size_t sC)
{
    gemm_core<8192, 4096, 1024, 1024, 4, true, false>(A, Bm, C, sA, sB, sC);
}

// ---------------- 256^2 sub-phased pipelined core (m201-style) -------------
// 512 threads = 8 waves (2 row-halves x 4 col-quarters), per-wave C = 128x64
// (acc[8][4]), BK=32, mfma_f32_16x16x32_bf16.
// LDS: 4-deep circular K-tile buffers, buf = kt&3: [A 256x32 | B 256x32] =
// 32KB; 4 bufs = 128KB -> 1 wg/CU (8 waves, 2/SIMD).
// Per K-tile t, TWO sub-phases (m201 template):
//   subA: ds_read af[0..7]+bfr[0..1] (10x b128); stage A-half of kt t+3;
//         s_barrier; lgkmcnt(0); setprio(1); 16 MFMA (nt 0,1); setprio(0);
//         s_barrier.
//   subB: ds_read bfr[2..3]; stage B-half of kt t+3; s_barrier; lgkmcnt(0);
//         setprio(1); 16 MFMA (nt 2,3); setprio(0); vmcnt(8); s_barrier.
// vmcnt(8) = 2 younger K-tiles (8 loads) stay in flight, never drained in
// main loop; epilogue 8->4->0. lgkmcnt(0) before each closing barrier makes
// the WAR (stage overwrites buf (t-1)&3, read last iter) airtight.
template <int LDA, int LDB, int LDC, int KLEN, int SLICES, bool PARTIAL>
__device__ __forceinline__ void gemm256_core(
    const unsigned short* __restrict__ A,
    const unsigned short* __restrict__ Bm,
    float* __restrict__ C, size_t sA, size_t sB, size_t sC)
{
    const int bz = blockIdx.z;
    const int batch = bz / SLICES;
    const int slice = bz % SLICES;
    A  += (size_t)batch * sA;
    Bm += (size_t)batch * sB;
    C  += PARTIAL ? (size_t)bz * sC : (size_t)batch * sC;
    const int koff = slice * KLEN;

    const int m0 = blockIdx.y * 256;
    const int n0 = blockIdx.x * 256;

    __shared__ unsigned short lds[4 * 16384];   // 128 KiB

    const int tid  = threadIdx.x;           // 0..511
    const int lane = tid & 63;
    const int wid  = tid >> 6;              // 0..7
    const int wm   = wid >> 2;              // 0..1: 128-row half
    const int wn   = wid & 3;               // 0..3: 64-col quarter
    const int l15  = lane & 15, q = lane >> 4;
    const int lrow = lane >> 2;
    const int cgl  = (lane & 3) ^ ((lane >> 3) & 3);
    const int qx   = q ^ ((l15 >> 1) & 3);

    f32x4 acc[8][4];
#pragma unroll
    for (int a = 0; a < 8; a++)
#pragma unroll
        for (int b = 0; b < 4; b++) acc[a][b] = (f32x4){0.f, 0.f, 0.f, 0.f};

    const int NT = KLEN / 32;               // 64 K-tiles

    // Per-thread staging sources (2 A-chunks + 2 B-chunks of 16 rows x 32k).
    const int c0 = (wid * 2 + 0) * 512;
    const int c1 = (wid * 2 + 1) * 512;
    const unsigned short* aS0 = &A[(size_t)(m0 + (wid * 2 + 0) * 16 + lrow) * LDA + koff + cgl * 8];
    const unsigned short* aS1 = &A[(size_t)(m0 + (wid * 2 + 1) * 16 + lrow) * LDA + koff + cgl * 8];
    const unsigned short* bS0 = &Bm[(size_t)(n0 + (wid * 2 + 0) * 16 + lrow) * LDB + koff + cgl * 8];
    const unsigned short* bS1 = &Bm[(size_t)(n0 + (wid * 2 + 1) * 16 + lrow) * LDB + koff + cgl * 8];

    auto STAGE_A = [&](int kt) {
        unsigned short* buf = &lds[(kt & 3) * 16384];
        async_load16(aS0 + (size_t)kt * 32, &buf[c0]);
        async_load16(aS1 + (size_t)kt * 32, &buf[c1]);
    };
    auto STAGE_B = [&](int kt) {
        unsigned short* buf = &lds[(kt & 3) * 16384];
        async_load16(bS0 + (size_t)kt * 32, &buf[8192 + c0]);
        async_load16(bS1 + (size_t)kt * 32, &buf[8192 + c1]);
    };

    // One K-tile iteration: two barrier-paired 16-MFMA sub-phases.
    // vm: 8 = steady-state counted wait, 4/0 = epilogue drain, -1 = none.
    auto ITER = [&](int t, bool doStage, int vm) {
        const unsigned short* buf = &lds[(t & 3) * 16384];
        bf16x8 af[8], bfr[4];
        // ---- sub-phase A ----
#pragma unroll
        for (int mt = 0; mt < 8; mt++)
            af[mt] = *(const bf16x8*)&buf[((wm * 128 + mt * 16 + l15) * 4 + qx) * 8];
#pragma unroll
        for (int nt = 0; nt < 2; nt++)
            bfr[nt] = *(const bf16x8*)&buf[8192 + ((wn * 64 + nt * 16 + l15) * 4 + qx) * 8];
        if (doStage) STAGE_A(t + 3);
        asm volatile("s_barrier" ::: "memory");
        asm volatile("s_waitcnt lgkmcnt(0)" ::: "memory");
        __builtin_amdgcn_s_setprio(1);
#pragma unroll
        for (int mt = 0; mt < 8; mt++)
#pragma unroll
            for (int nt = 0; nt < 2; nt++)
                acc[mt][nt] = __builtin_amdgcn_mfma_f32_16x16x32_bf16(
                    af[mt], bfr[nt], acc[mt][nt], 0, 0, 0);
        __builtin_amdgcn_s_setprio(0);
        asm volatile("s_barrier" ::: "memory");
        // ---- sub-phase B ----
#pragma unroll
        for (int nt = 2; nt < 4; nt++)
            bfr[nt] = *(const bf16x8*)&buf[8192 + ((wn * 64 + nt * 16 + l15) * 4 + qx) * 8];
        if (doStage) STAGE_B(t + 3);
        asm volatile("s_barrier" ::: "memory");
        asm volatile("s_waitcnt lgkmcnt(0)" ::: "memory");
        __builtin_amdgcn_s_setprio(1);
#pragma unroll
        for (int mt = 0; mt < 8; mt++)
#pragma unroll
            for (int nt = 2; nt < 4; nt++)
                acc[mt][nt] = __builtin_amdgcn_mfma_f32_16x16x32_bf16(
                    af[mt], bfr[nt], acc[mt][nt], 0, 0, 0);
        __builtin_amdgcn_s_setprio(0);
        if (vm == 8)      asm volatile("s_waitcnt vmcnt(8)" ::: "memory");
        else if (vm == 4) asm volatile("s_waitcnt vmcnt(4)" ::: "memory");
        else if (vm == 0) asm volatile("s_waitcnt vmcnt(0)" ::: "memory");
        asm volatile("s_barrier" ::: "memory");
    };

    // Prologue: stage K-tiles 0..2 (12 loads/thread), wait kt0 (drain to 8).
    STAGE_A(0); STAGE_B(0);
    STAGE_A(1); STAGE_B(1);
    STAGE_A(2); STAGE_B(2);
    asm volatile("s_waitcnt vmcnt(8)" ::: "memory");
    asm volatile("s_barrier" ::: "memory");

    for (int t = 0; t < NT - 3; ++t)
        ITER(t, true, 8);
    ITER(NT - 3, false, 4);
    ITER(NT - 2, false, 0);
    ITER(NT - 1, false, -1);

#pragma unroll
    for (int mt = 0; mt < 8; mt++) {
#pragma unroll
        for (int nt = 0; nt < 4; nt++) {
            const int n = n0 + wn * 64 + nt * 16 + l15;
#pragma unroll
            for (int r = 0; r < 4; r++) {
                const int m = m0 + wm * 128 + mt * 16 + q * 4 + r;
                C[(size_t)m * LDC + n] = acc[mt][nt][r];
            }
        }
    }
}

__global__ __launch_bounds__(512, 2) void k2_gemm256(
    const unsigned short* __restrict__ A, const unsigned short* __restrict__ Bm,
    float* __restrict__ C, size_t sA, size_t sB, size_t sC)
{
    gemm256_core<2048, 2048, 4096, 2048, 1, false>(A, Bm, C, sA, sB, sC);
}

__global__ __launch_bounds__(512, 2) void k4_gemm256(
    const unsigned short* __restrict__ A, const unsigned short* __restrict__ Bm,
    float* __restrict__ C, size_t sA, size_t sB, size_t sC)
{
    gemm256_core<8192, 4096, 1024, 2048, 2, true>(A, Bm, C, sA, sB, sC);
}

// ---------------- K5: reduce partials -> out ----------------
__global__ __launch_bounds__(256) void reduce_kernel(
    const float* __restrict__ part, float* __restrict__ out)
{
    int j4 = blockIdx.x * 256 + threadIdx.x;      // float4 index, < 2*1048576
    int b  = j4 >> 20;
    int jj = j4 & 1048575;
    const float4* p0 = (const float4*)(part + (size_t)(b * 2 + 0) * 4194304);
    const float4* p1 = (const float4*)(part + (size_t)(b * 2 + 1) * 4194304);
    float4 a = p0[jj], c = p1[jj];
    float4 r; r.x = a.x + c.x; r.y = a.y + c.y; r.z = a.z + c.z; r.w = a.w + c.w;
    ((float4*)out)[j4] = r;
}

// ---------------- K3: row softmax, fp32 sim -> bf16 P in place -------------
__global__ __launch_bounds__(256) void softmax_kernel(float* __restrict__ simbase,
                                                      size_t batchStride)
{
    const int row = blockIdx.x;
    float* sim = simbase + (size_t)(row >> 12) * batchStride;
    const int r = row & 4095;
    const float* pin = sim + (size_t)r * 4096;
    unsigned short* pout = (unsigned short*)sim + (size_t)r * 8192;
    const int tid = threadIdx.x;

    float v[16];
#pragma unroll
    for (int i = 0; i < 4; i++) {
        float4 d = ((const float4*)pin)[tid * 4 + i];
        v[4 * i + 0] = d.x * 0.03125f;
        v[4 * i + 1] = d.y * 0.03125f;
        v[4 * i + 2] = d.z * 0.03125f;
        v[4 * i + 3] = d.w * 0.03125f;
    }

    float m = v[0];
#pragma unroll
    for (int i = 1; i < 16; i++) m = fmaxf(m, v[i]);
    for (int o = 32; o > 0; o >>= 1) m = fmaxf(m, __shfl_xor(m, o));
    __shared__ float red[4];
    if ((tid & 63) == 0) red[tid >> 6] = m;
    __syncthreads();
    m = fmaxf(fmaxf(red[0], red[1]), fmaxf(red[2], red[3]));
    __syncthreads();

    float e[16];
    float s = 0.f;
#pragma unroll
    for (int i = 0; i < 16; i++) { e[i] = expf(v[i] - m); s += e[i]; }
    for (int o = 32; o > 0; o >>= 1) s += __shfl_xor(s, o);
    if ((tid & 63) == 0) red[tid >> 6] = s;
    __syncthreads();
    float l = (red[0] + red[1]) + (red[2] + red[3]);
    float inv = 1.0f / l;

#pragma unroll
    for (int c = 0; c < 2; c++) {
        unsigned int wds[4];
#pragma unroll
        for (int i = 0; i < 4; i++) {
            unsigned int lo = f2b(e[c * 8 + 2 * i] * inv);
            unsigned int hi = f2b(e[c * 8 + 2 * i + 1] * inv);
            wds[i] = lo | (hi << 16);
        }
        uint4 o4; o4.x = wds[0]; o4.y = wds[1]; o4.z = wds[2]; o4.w = wds[3];
        ((uint4*)pout)[tid * 2 + c] = o4;
    }
}

extern "C" void kernel_launch(void* const* d_in, const int* in_sizes, int n_in,
                              void* d_out, int out_size, void* d_ws, size_t ws_size,
                              hipStream_t stream)
{
    const float* x  = (const float*)d_in[0];
    const float* Wq = (const float*)d_in[1];
    const float* bq = (const float*)d_in[2];
    const float* Wk = (const float*)d_in[3];
    const float* bk = (const float*)d_in[4];
    const float* Wv = (const float*)d_in[5];
    const float* bv = (const float*)d_in[6];
    const float* ph = (const float*)d_in[7];

    char* ws = (char*)d_ws;
    const size_t SIMB = (size_t)4096 * 4096 * 4;                  // 67.1MB
    unsigned short* Xhi = (unsigned short*)ws;                    // aliases sim0
    unsigned short* Xlo = Xhi + (size_t)8192 * 1024;
    unsigned short* Whi = Xlo + (size_t)8192 * 1024;
    unsigned short* Wlo = Whi + (size_t)3072 * 1024;
    float*          sim0 = (float*)ws;
    unsigned short* Qf = (unsigned short*)(ws + SIMB);            // [2][4096][2048]
    unsigned short* Kf = Qf + (size_t)2 * 4096 * 2048;            // [2][4096][2048]
    unsigned short* Vt = Kf + (size_t)2 * 4096 * 2048;            // [2][1024][4096]
    float*          sim1 = (float*)(ws + SIMB + (size_t)83886080); // after Vt
    float*          part = (float*)(ws + SIMB);                   // aliases Qf+Kf (dead after k2)
    const bool twoSim = ws_size >= (size_t)218103808;

    split_kernel<<<8192, 256, 0, stream>>>(x, Xhi, Xlo, 8192 * 1024 / 4);
    split_w_kernel<<<dim3(1024, 3), 256, 0, stream>>>(Wq, Wk, Wv, Whi, Wlo);
    proj_kernel<<<dim3(24, 64), 256, 0, stream>>>(Xhi, Xlo, Whi, Wlo,
                                                  bq, bk, bv, ph, Qf, Kf, Vt);

    const size_t sQK = (size_t)4096 * 2048;    // Qf/Kf batch stride (shorts)
    const size_t sV  = (size_t)1024 * 4096;    // Vt batch stride (shorts)
    const size_t sO  = (size_t)4096 * 1024;    // out / partial stride (floats)

    if (twoSim) {
        const size_t sSim = (size_t)(sim1 - sim0);   // floats between sims
        k2_gemm256<<<dim3(16, 16, 2), 512, 0, stream>>>(Qf, Kf, sim0, sQK, sQK, sSim);
        softmax_kernel<<<8192, 256, 0, stream>>>(sim0, sSim);
        // out partials: z = batch*2 + slice, each slice K=2048 of 4096
        k4_gemm256<<<dim3(4, 16, 4), 512, 0, stream>>>((const unsigned short*)sim0, Vt,
                                                       part, sSim * 2, sV, sO);
        reduce_kernel<<<8192, 256, 0, stream>>>(part, (float*)d_out);
    } else {
        hipMemsetAsync(d_out, 0, (size_t)2 * 4096 * 1024 * sizeof(float), stream);
        for (int b = 0; b < 2; b++) {
            const unsigned short* Qb = Qf + (size_t)b * sQK;
            const unsigned short* Kb = Kf + (size_t)b * sQK;
            const unsigned short* Vb = Vt + (size_t)b * sV;
            float* outb = (float*)d_out + (size_t)b * sO;
            k2_gemm256<<<dim3(16, 16, 1), 512, 0, stream>>>(Qb, Kb, sim0, 0, 0, 0);
            softmax_kernel<<<4096, 256, 0, stream>>>(sim0, 0);
            k4_gemm_atomic<<<dim3(8, 32, 4), 256, 0, stream>>>(
                (const unsigned short*)sim0, Vb, outb, 0, 0, 0);
        }
    }
}

// Round 4
// 507.901 us; speedup vs baseline: 1.0669x; 1.0062x over previous
//
#include <hip/hip_runtime.h>
#include <math.h>

// EulerAttention: B=2, S=4096, D=1024.
// Pipeline: [K0] split fp32 -> (hi,lo) bf16 for x and stacked W  (elementwise)
//           [K1] split-bf16 MFMA GEMM (3-term), M=8192 N=3072 K=1024,
//                epilogue: bias + HW-trig sincos -> Qf/Kf bf16 features, V -> Vt
//           [K2] 256^2-tile sub-phased pipelined bf16 NT GEMM (z=2): sim = Qf@Kf^T
//           [K3] row softmax: fp32 sim -> bf16 P in place (row stride 8192)
//           [K4] same 256^2 core, split-K x2 -> separate fp32 partials
//           [K5] float4 reduce -> out
// ws (two-sim mode, 218MB): [sim0 67MB (aliases split bufs)][Qf 33.5][Kf 33.5]
//   [Vt 16.8][sim1 67]. Partials alias Qf+Kf after K2. Fallback <218MB:
//   sequential per-batch, atomic split-K k4 (old 128^2 core).
//
// Precision notes (load-bearing):
//  - sim ~ 640 +- ~15. sim MUST be fp32 (R1 failure).
//  - Q/K need near-fp32: inv_wl[0]~163 amplifies Q error. 3-term split-bf16.
//  - R3 failure: libm sincosf -> scratch spill. Trig MUST be inline v_sin/v_cos.
// Perf notes:
//  - R11 stacked-K deep-pipe proj REGRESSED (233us, +45% L2 traffic). Reverted.
//  - R12: m201-style sub-phases in gemm256 = NEUTRAL vs coarse (508 vs 511).
//    Diagnosis: k2/k4 staging is L2/L3-BW-bound (~570cyc/K-tile of 32KB/CU
//    staging vs 310cyc MFMA), NOT schedule-bound. Schedule micro-structure
//    can't help; locality might (XCD swizzle added as A/B, expected +-3%).
//  - R13 (this): proj bank-conflict fix. Old *40-pad layout = 2.5e7
//    conflict-cycles/dispatch (~22% of proj time): b128 frags at
//    bank-group (5r+q)%8, ~3-way/quarter-wave. Ported the VERIFIED
//    zero-conflict gemm256 layout (stride 32 + XOR slot swizzle:
//    write slot cc^((row>>1)&3), read slot q^((l15>>1)&3)). LDS 40->32KB,
//    occupancy 2->3 blocks/CU.

typedef __attribute__((ext_vector_type(8))) short bf16x8;
typedef __attribute__((ext_vector_type(4))) float f32x4;

__device__ __forceinline__ float b2f(unsigned short h) {
    union { unsigned int u; float f; } v; v.u = ((unsigned int)h) << 16; return v.f;
}
__device__ __forceinline__ unsigned short f2b(float f) {
    union { float f; unsigned int u; } v; v.f = f;
    unsigned int r = v.u + 0x7fffu + ((v.u >> 16) & 1u);
    return (unsigned short)(r >> 16);
}

// Async global->LDS 16B per lane. LDS dest = wave-uniform base + lane*16.
__device__ __forceinline__ void async_load16(const unsigned short* g, unsigned short* l) {
    __builtin_amdgcn_global_load_lds(
        (const __attribute__((address_space(1))) unsigned int*)g,
        (__attribute__((address_space(3))) unsigned int*)l, 16, 0, 0);
}

// Branch-free sin/cos of th (radians). HW v_sin/v_cos take REVOLUTIONS.
__device__ __forceinline__ void fast_sincos(float th, float* sn, float* cs) {
    float rev = th * 0.15915494309189535f;
    float fr  = rev - floorf(rev);
    float s, c;
    asm("v_sin_f32 %0, %1" : "=v"(s) : "v"(fr));
    asm("v_cos_f32 %0, %1" : "=v"(c) : "v"(fr));
    *sn = s; *cs = c;
}

// ---------------- K0: fp32 -> (hi, lo) bf16 split ----------------
__global__ __launch_bounds__(256) void split_kernel(
    const float* __restrict__ src,
    unsigned short* __restrict__ hi, unsigned short* __restrict__ lo, int n4)
{
    int i = blockIdx.x * 256 + threadIdx.x;
    if (i >= n4) return;
    float4 v = ((const float4*)src)[i];
    float f[4] = { v.x, v.y, v.z, v.w };
    unsigned short h[4], l[4];
#pragma unroll
    for (int j = 0; j < 4; j++) {
        h[j] = f2b(f[j]);
        float r = f[j] - b2f(h[j]);
        l[j] = f2b(r);
    }
    uint2 ho, lv;
    ho.x = (unsigned int)h[0] | ((unsigned int)h[1] << 16);
    ho.y = (unsigned int)h[2] | ((unsigned int)h[3] << 16);
    lv.x = (unsigned int)l[0] | ((unsigned int)l[1] << 16);
    lv.y = (unsigned int)l[2] | ((unsigned int)l[3] << 16);
    ((uint2*)hi)[i] = ho;
    ((uint2*)lo)[i] = lv;
}

__global__ __launch_bounds__(256) void split_w_kernel(
    const float* __restrict__ Wq, const float* __restrict__ Wk,
    const float* __restrict__ Wv,
    unsigned short* __restrict__ hi, unsigned short* __restrict__ lo)
{
    const int y = blockIdx.y;
    const float* src = (y == 0) ? Wq : ((y == 1) ? Wk : Wv);
    size_t off4 = (size_t)y * (1024 * 1024 / 4);
    int i = blockIdx.x * 256 + threadIdx.x;
    float4 v = ((const float4*)src)[i];
    float f[4] = { v.x, v.y, v.z, v.w };
    unsigned short h[4], l[4];
#pragma unroll
    for (int j = 0; j < 4; j++) {
        h[j] = f2b(f[j]);
        float r = f[j] - b2f(h[j]);
        l[j] = f2b(r);
    }
    uint2 ho, lv;
    ho.x = (unsigned int)h[0] | ((unsigned int)h[1] << 16);
    ho.y = (unsigned int)h[2] | ((unsigned int)h[3] << 16);
    lv.x = (unsigned int)l[0] | ((unsigned int)l[1] << 16);
    lv.y = (unsigned int)l[2] | ((unsigned int)l[3] << 16);
    ((uint2*)hi)[off4 + i] = ho;
    ((uint2*)lo)[off4 + i] = lv;
}

// ---------------- K1: split-bf16 MFMA projection GEMM ----------------
// R13: LDS layout = gemm256's verified zero-conflict scheme. Row stride 32
// shorts (64B, 4x 16B slots). k-chunk kc stored at slot kc^((row>>1)&3);
// fragment read (row, q) at slot q^((row>>1)&3) (= qx, row-invariant since
// row = base16*k + l15 and base is 0 mod 8).
__global__ __launch_bounds__(256, 3) void proj_kernel(
    const unsigned short* __restrict__ Xhi, const unsigned short* __restrict__ Xlo,
    const unsigned short* __restrict__ Whi, const unsigned short* __restrict__ Wlo,
    const float* __restrict__ bq, const float* __restrict__ bk,
    const float* __restrict__ bv, const float* __restrict__ phase,
    unsigned short* __restrict__ Qf, unsigned short* __restrict__ Kf,
    unsigned short* __restrict__ Vt)
{
    const int m0 = blockIdx.y * 128;
    const int n0 = blockIdx.x * 128;

    __shared__ unsigned short Ah[128 * 32], Al[128 * 32];
    __shared__ unsigned short Bh[128 * 32], Bl[128 * 32];

    const int tid  = threadIdx.x;
    const int lane = tid & 63;
    const int w    = tid >> 6;
    const int wr   = w >> 1, wc = w & 1;
    const int l15  = lane & 15, q = lane >> 4;
    const int qx   = q ^ ((l15 >> 1) & 3);

    f32x4 acc[4][4];
#pragma unroll
    for (int a = 0; a < 4; a++)
#pragma unroll
        for (int b = 0; b < 4; b++) acc[a][b] = (f32x4){0.f, 0.f, 0.f, 0.f};

    for (int k0 = 0; k0 < 1024; k0 += 32) {
#pragma unroll
        for (int i = 0; i < 2; i++) {
            int idx = tid + 256 * i;
            int row = idx >> 2;
            int cc  = idx & 3;
            int scc = cc ^ ((row >> 1) & 3);
            size_t ga = (size_t)(m0 + row) * 1024 + k0 + cc * 8;
            size_t gb = (size_t)(n0 + row) * 1024 + k0 + cc * 8;
            *(uint4*)&Ah[(row * 4 + scc) * 8] = *(const uint4*)&Xhi[ga];
            *(uint4*)&Al[(row * 4 + scc) * 8] = *(const uint4*)&Xlo[ga];
            *(uint4*)&Bh[(row * 4 + scc) * 8] = *(const uint4*)&Whi[gb];
            *(uint4*)&Bl[(row * 4 + scc) * 8] = *(const uint4*)&Wlo[gb];
        }
        __syncthreads();
        bf16x8 ah[4], al[4];
#pragma unroll
        for (int mt = 0; mt < 4; mt++) {
            int off = ((wr * 64 + mt * 16 + l15) * 4 + qx) * 8;
            ah[mt] = *(const bf16x8*)&Ah[off];
            al[mt] = *(const bf16x8*)&Al[off];
        }
#pragma unroll
        for (int nt = 0; nt < 4; nt++) {
            int off = ((wc * 64 + nt * 16 + l15) * 4 + qx) * 8;
            bf16x8 bh = *(const bf16x8*)&Bh[off];
            bf16x8 bl = *(const bf16x8*)&Bl[off];
#pragma unroll
            for (int mt = 0; mt < 4; mt++) {
                acc[mt][nt] = __builtin_amdgcn_mfma_f32_16x16x32_bf16(
                    ah[mt], bh, acc[mt][nt], 0, 0, 0);
                acc[mt][nt] = __builtin_amdgcn_mfma_f32_16x16x32_bf16(
                    ah[mt], bl, acc[mt][nt], 0, 0, 0);
                acc[mt][nt] = __builtin_amdgcn_mfma_f32_16x16x32_bf16(
                    al[mt], bh, acc[mt][nt], 0, 0, 0);
            }
        }
        __syncthreads();
    }

    const int z = n0 >> 10;                   // 0=Q, 1=K, 2=V
    const float* bias = (z == 0) ? bq : ((z == 1) ? bk : bv);
    const float w0 = (float)(2.0 * M_PI / 1024.0);

#pragma unroll
    for (int mt = 0; mt < 4; mt++) {
#pragma unroll
        for (int nt = 0; nt < 4; nt++) {
            int n = n0 + wc * 64 + nt * 16 + l15;
            int f = n & 1023;
            float bsv = bias[f];
            float wl  = (float)(f + 1) * w0;
            float inv = 1.0f / (wl + 1e-8f);
            float phv = phase[f];
#pragma unroll
            for (int r = 0; r < 4; r++) {
                int m  = m0 + wr * 64 + mt * 16 + q * 4 + r;
                int bb = m >> 12;
                int s  = m & 4095;
                float val = acc[mt][nt][r] + bsv;
                if (z == 2) {
                    Vt[((size_t)bb * 1024 + f) * 4096 + s] = f2b(val);
                } else {
                    float th = fmaf(val, inv, phv);
                    float sn, cs;
                    fast_sincos(th, &sn, &cs);
                    unsigned short* dst = (z == 0) ? Qf : Kf;
                    size_t base = ((size_t)bb * 4096 + s) * 2048;
                    dst[base + f]        = f2b(cs);
                    dst[base + 1024 + f] = f2b(sn);
                }
            }
        }
    }
}

// ---------------- old 128^2 core: kept ONLY for atomic fallback ------------
template <int LDA, int LDB, int LDC, int KLEN, int SLICES, bool ATOMIC, bool PARTIAL>
__device__ __forceinline__ void gemm_core(
    const unsigned short* __restrict__ A,
    const unsigned short* __restrict__ Bm,
    float* __restrict__ C, size_t sA, size_t sB, size_t sC)
{
    const int bz = blockIdx.z;
    const int batch = bz / SLICES;
    const int slice = bz % SLICES;
    A  += (size_t)batch * sA;
    Bm += (size_t)batch * sB;
    C  += PARTIAL ? (size_t)bz * sC : (size_t)batch * sC;
    const int koff = slice * KLEN;

    const int m0 = blockIdx.y * 128;
    const int n0 = blockIdx.x * 128;

    __shared__ unsigned short As[128 * 32];
    __shared__ unsigned short Bs[128 * 32];

    const int tid  = threadIdx.x;
    const int lane = tid & 63;
    const int w    = tid >> 6;
    const int wr   = w >> 1, wc = w & 1;
    const int l15  = lane & 15, q = lane >> 4;
    const int lrow = lane >> 2;
    const int cgl  = (lane & 3) ^ ((lane >> 3) & 3);
    const int qx   = q ^ ((l15 >> 1) & 3);

    f32x4 acc[4][4];
#pragma unroll
    for (int a = 0; a < 4; a++)
#pragma unroll
        for (int b = 0; b < 4; b++) acc[a][b] = (f32x4){0.f, 0.f, 0.f, 0.f};

    for (int k0 = 0; k0 < KLEN; k0 += 32) {
        int kg = koff + k0;
#pragma unroll
        for (int i = 0; i < 2; i++) {
            int chunk = w * 2 + i;
            async_load16(&A[(size_t)(m0 + chunk * 16 + lrow) * LDA + kg + cgl * 8],
                         &As[chunk * 512]);
            async_load16(&Bm[(size_t)(n0 + chunk * 16 + lrow) * LDB + kg + cgl * 8],
                         &Bs[chunk * 512]);
        }
        __syncthreads();
        bf16x8 af[4], bfr[4];
#pragma unroll
        for (int mt = 0; mt < 4; mt++) {
            int ar = wr * 64 + mt * 16 + l15;
            af[mt] = *(const bf16x8*)&As[(ar * 4 + qx) * 8];
        }
#pragma unroll
        for (int nt = 0; nt < 4; nt++) {
            int br = wc * 64 + nt * 16 + l15;
            bfr[nt] = *(const bf16x8*)&Bs[(br * 4 + qx) * 8];
        }
#pragma unroll
        for (int mt = 0; mt < 4; mt++)
#pragma unroll
            for (int nt = 0; nt < 4; nt++)
                acc[mt][nt] = __builtin_amdgcn_mfma_f32_16x16x32_bf16(
                    af[mt], bfr[nt], acc[mt][nt], 0, 0, 0);
        __syncthreads();
    }

#pragma unroll
    for (int mt = 0; mt < 4; mt++) {
#pragma unroll
        for (int nt = 0; nt < 4; nt++) {
            int n = n0 + wc * 64 + nt * 16 + l15;
#pragma unroll
            for (int r = 0; r < 4; r++) {
                int m = m0 + wr * 64 + mt * 16 + q * 4 + r;
                float* p = &C[(size_t)m * LDC + n];
                if (ATOMIC)
                    __hip_atomic_fetch_add(p, acc[mt][nt][r],
                                           __ATOMIC_RELAXED, __HIP_MEMORY_SCOPE_AGENT);
                else
                    *p = acc[mt][nt][r];
            }
        }
    }
}

// k4 fallback path (one sim): atomic split-K x4 within one batch.
__global__ __launch_bounds__(256) void k4_gemm_atomic(
    const unsigned short* __restrict__ A, const unsigned short* __restrict__ Bm,
    float* __restrict__ C, size_t sA, size_t sB, size_t sC)
{
    gemm_core<8192, 4096, 1024, 1024, 4, true, false>(A, Bm, C, sA, sB, sC);
}

// ---------------- 256^2 sub-phased pipelined core (m201-style) -------------
// 512 threads = 8 waves (2 row-halves x 4 col-quarters), per-wave C = 128x64
// (acc[8][4]), BK=32, mfma_f32_16x16x32_bf16.
// LDS: 4-deep circular K-tile buffers, buf = kt&3: [A 256x32 | B 256x32] =
// 32KB; 4 bufs = 128KB -> 1 wg/CU (8 waves, 2/SIMD).
// R12 note: sub-phases vs coarse measured NEUTRAL -> staging (L2/L3 BW) is
// the limiter, not schedule. R13 adds bijective XCD-chunked block swizzle
// (GX = gridDim.x, per-z nwg % 8 == 0) as a locality A/B.
template <int GX, int LDA, int LDB, int LDC, int KLEN, int SLICES, bool PARTIAL>
__device__ __forceinline__ void gemm256_core(
    const unsigned short* __restrict__ A,
    const unsigned short* __restrict__ Bm,
    float* __restrict__ C, size_t sA, size_t sB, size_t sC)
{
    const int bz = blockIdx.z;
    const int batch = bz / SLICES;
    const int slice = bz % SLICES;
    A  += (size_t)batch * sA;
    Bm += (size_t)batch * sB;
    C  += PARTIAL ? (size_t)bz * sC : (size_t)batch * sC;
    const int koff = slice * KLEN;

    // XCD-chunked bijective swizzle within this z-slice (nwg = GX*16, %8==0).
    const int nwg = GX * 16;
    const int lin = blockIdx.x + GX * blockIdx.y;
    const int nb  = (lin & 7) * (nwg >> 3) + (lin >> 3);
    const int m0 = (nb / GX) * 256;
    const int n0 = (nb % GX) * 256;

    __shared__ unsigned short lds[4 * 16384];   // 128 KiB

    const int tid  = threadIdx.x;           // 0..511
    const int lane = tid & 63;
    const int wid  = tid >> 6;              // 0..7
    const int wm   = wid >> 2;              // 0..1: 128-row half
    const int wn   = wid & 3;               // 0..3: 64-col quarter
    const int l15  = lane & 15, q = lane >> 4;
    const int lrow = lane >> 2;
    const int cgl  = (lane & 3) ^ ((lane >> 3) & 3);
    const int qx   = q ^ ((l15 >> 1) & 3);

    f32x4 acc[8][4];
#pragma unroll
    for (int a = 0; a < 8; a++)
#pragma unroll
        for (int b = 0; b < 4; b++) acc[a][b] = (f32x4){0.f, 0.f, 0.f, 0.f};

    const int NT = KLEN / 32;               // 64 K-tiles

    // Per-thread staging sources (2 A-chunks + 2 B-chunks of 16 rows x 32k).
    const int c0 = (wid * 2 + 0) * 512;
    const int c1 = (wid * 2 + 1) * 512;
    const unsigned short* aS0 = &A[(size_t)(m0 + (wid * 2 + 0) * 16 + lrow) * LDA + koff + cgl * 8];
    const unsigned short* aS1 = &A[(size_t)(m0 + (wid * 2 + 1) * 16 + lrow) * LDA + koff + cgl * 8];
    const unsigned short* bS0 = &Bm[(size_t)(n0 + (wid * 2 + 0) * 16 + lrow) * LDB + koff + cgl * 8];
    const unsigned short* bS1 = &Bm[(size_t)(n0 + (wid * 2 + 1) * 16 + lrow) * LDB + koff + cgl * 8];

    auto STAGE_A = [&](int kt) {
        unsigned short* buf = &lds[(kt & 3) * 16384];
        async_load16(aS0 + (size_t)kt * 32, &buf[c0]);
        async_load16(aS1 + (size_t)kt * 32, &buf[c1]);
    };
    auto STAGE_B = [&](int kt) {
        unsigned short* buf = &lds[(kt & 3) * 16384];
        async_load16(bS0 + (size_t)kt * 32, &buf[8192 + c0]);
        async_load16(bS1 + (size_t)kt * 32, &buf[8192 + c1]);
    };

    // One K-tile iteration: two barrier-paired 16-MFMA sub-phases.
    // vm: 8 = steady-state counted wait, 4/0 = epilogue drain, -1 = none.
    auto ITER = [&](int t, bool doStage, int vm) {
        const unsigned short* buf = &lds[(t & 3) * 16384];
        bf16x8 af[8], bfr[4];
        // ---- sub-phase A ----
#pragma unroll
        for (int mt = 0; mt < 8; mt++)
            af[mt] = *(const bf16x8*)&buf[((wm * 128 + mt * 16 + l15) * 4 + qx) * 8];
#pragma unroll
        for (int nt = 0; nt < 2; nt++)
            bfr[nt] = *(const bf16x8*)&buf[8192 + ((wn * 64 + nt * 16 + l15) * 4 + qx) * 8];
        if (doStage) STAGE_A(t + 3);
        asm volatile("s_barrier" ::: "memory");
        asm volatile("s_waitcnt lgkmcnt(0)" ::: "memory");
        __builtin_amdgcn_s_setprio(1);
#pragma unroll
        for (int mt = 0; mt < 8; mt++)
#pragma unroll
            for (int nt = 0; nt < 2; nt++)
                acc[mt][nt] = __builtin_amdgcn_mfma_f32_16x16x32_bf16(
                    af[mt], bfr[nt], acc[mt][nt], 0, 0, 0);
        __builtin_amdgcn_s_setprio(0);
        asm volatile("s_barrier" ::: "memory");
        // ---- sub-phase B ----
#pragma unroll
        for (int nt = 2; nt < 4; nt++)
            bfr[nt] = *(const bf16x8*)&buf[8192 + ((wn * 64 + nt * 16 + l15) * 4 + qx) * 8];
        if (doStage) STAGE_B(t + 3);
        asm volatile("s_barrier" ::: "memory");
        asm volatile("s_waitcnt lgkmcnt(0)" ::: "memory");
        __builtin_amdgcn_s_setprio(1);
#pragma unroll
        for (int mt = 0; mt < 8; mt++)
#pragma unroll
            for (int nt = 2; nt < 4; nt++)
                acc[mt][nt] = __builtin_amdgcn_mfma_f32_16x16x32_bf16(
                    af[mt], bfr[nt], acc[mt][nt], 0, 0, 0);
        __builtin_amdgcn_s_setprio(0);
        if (vm == 8)      asm volatile("s_waitcnt vmcnt(8)" ::: "memory");
        else if (vm == 4) asm volatile("s_waitcnt vmcnt(4)" ::: "memory");
        else if (vm == 0) asm volatile("s_waitcnt vmcnt(0)" ::: "memory");
        asm volatile("s_barrier" ::: "memory");
    };

    // Prologue: stage K-tiles 0..2 (12 loads/thread), wait kt0 (drain to 8).
    STAGE_A(0); STAGE_B(0);
    STAGE_A(1); STAGE_B(1);
    STAGE_A(2); STAGE_B(2);
    asm volatile("s_waitcnt vmcnt(8)" ::: "memory");
    asm volatile("s_barrier" ::: "memory");

    for (int t = 0; t < NT - 3; ++t)
        ITER(t, true, 8);
    ITER(NT - 3, false, 4);
    ITER(NT - 2, false, 0);
    ITER(NT - 1, false, -1);

#pragma unroll
    for (int mt = 0; mt < 8; mt++) {
#pragma unroll
        for (int nt = 0; nt < 4; nt++) {
            const int n = n0 + wn * 64 + nt * 16 + l15;
#pragma unroll
            for (int r = 0; r < 4; r++) {
                const int m = m0 + wm * 128 + mt * 16 + q * 4 + r;
                C[(size_t)m * LDC + n] = acc[mt][nt][r];
            }
        }
    }
}

__global__ __launch_bounds__(512, 2) void k2_gemm256(
    const unsigned short* __restrict__ A, const unsigned short* __restrict__ Bm,
    float* __restrict__ C, size_t sA, size_t sB, size_t sC)
{
    gemm256_core<16, 2048, 2048, 4096, 2048, 1, false>(A, Bm, C, sA, sB, sC);
}

__global__ __launch_bounds__(512, 2) void k4_gemm256(
    const unsigned short* __restrict__ A, const unsigned short* __restrict__ Bm,
    float* __restrict__ C, size_t sA, size_t sB, size_t sC)
{
    gemm256_core<4, 8192, 4096, 1024, 2048, 2, true>(A, Bm, C, sA, sB, sC);
}

// ---------------- K5: reduce partials -> out ----------------
__global__ __launch_bounds__(256) void reduce_kernel(
    const float* __restrict__ part, float* __restrict__ out)
{
    int j4 = blockIdx.x * 256 + threadIdx.x;      // float4 index, < 2*1048576
    int b  = j4 >> 20;
    int jj = j4 & 1048575;
    const float4* p0 = (const float4*)(part + (size_t)(b * 2 + 0) * 4194304);
    const float4* p1 = (const float4*)(part + (size_t)(b * 2 + 1) * 4194304);
    float4 a = p0[jj], c = p1[jj];
    float4 r; r.x = a.x + c.x; r.y = a.y + c.y; r.z = a.z + c.z; r.w = a.w + c.w;
    ((float4*)out)[j4] = r;
}

// ---------------- K3: row softmax, fp32 sim -> bf16 P in place -------------
__global__ __launch_bounds__(256) void softmax_kernel(float* __restrict__ simbase,
                                                      size_t batchStride)
{
    const int row = blockIdx.x;
    float* sim = simbase + (size_t)(row >> 12) * batchStride;
    const int r = row & 4095;
    const float* pin = sim + (size_t)r * 4096;
    unsigned short* pout = (unsigned short*)sim + (size_t)r * 8192;
    const int tid = threadIdx.x;

    float v[16];
#pragma unroll
    for (int i = 0; i < 4; i++) {
        float4 d = ((const float4*)pin)[tid * 4 + i];
        v[4 * i + 0] = d.x * 0.03125f;
        v[4 * i + 1] = d.y * 0.03125f;
        v[4 * i + 2] = d.z * 0.03125f;
        v[4 * i + 3] = d.w * 0.03125f;
    }

    float m = v[0];
#pragma unroll
    for (int i = 1; i < 16; i++) m = fmaxf(m, v[i]);
    for (int o = 32; o > 0; o >>= 1) m = fmaxf(m, __shfl_xor(m, o));
    __shared__ float red[4];
    if ((tid & 63) == 0) red[tid >> 6] = m;
    __syncthreads();
    m = fmaxf(fmaxf(red[0], red[1]), fmaxf(red[2], red[3]));
    __syncthreads();

    float e[16];
    float s = 0.f;
#pragma unroll
    for (int i = 0; i < 16; i++) { e[i] = expf(v[i] - m); s += e[i]; }
    for (int o = 32; o > 0; o >>= 1) s += __shfl_xor(s, o);
    if ((tid & 63) == 0) red[tid >> 6] = s;
    __syncthreads();
    float l = (red[0] + red[1]) + (red[2] + red[3]);
    float inv = 1.0f / l;

#pragma unroll
    for (int c = 0; c < 2; c++) {
        unsigned int wds[4];
#pragma unroll
        for (int i = 0; i < 4; i++) {
            unsigned int lo = f2b(e[c * 8 + 2 * i] * inv);
            unsigned int hi = f2b(e[c * 8 + 2 * i + 1] * inv);
            wds[i] = lo | (hi << 16);
        }
        uint4 o4; o4.x = wds[0]; o4.y = wds[1]; o4.z = wds[2]; o4.w = wds[3];
        ((uint4*)pout)[tid * 2 + c] = o4;
    }
}

extern "C" void kernel_launch(void* const* d_in, const int* in_sizes, int n_in,
                              void* d_out, int out_size, void* d_ws, size_t ws_size,
                              hipStream_t stream)
{
    const float* x  = (const float*)d_in[0];
    const float* Wq = (const float*)d_in[1];
    const float* bq = (const float*)d_in[2];
    const float* Wk = (const float*)d_in[3];
    const float* bk = (const float*)d_in[4];
    const float* Wv = (const float*)d_in[5];
    const float* bv = (const float*)d_in[6];
    const float* ph = (const float*)d_in[7];

    char* ws = (char*)d_ws;
    const size_t SIMB = (size_t)4096 * 4096 * 4;                  // 67.1MB
    unsigned short* Xhi = (unsigned short*)ws;                    // aliases sim0
    unsigned short* Xlo = Xhi + (size_t)8192 * 1024;
    unsigned short* Whi = Xlo + (size_t)8192 * 1024;
    unsigned short* Wlo = Whi + (size_t)3072 * 1024;
    float*          sim0 = (float*)ws;
    unsigned short* Qf = (unsigned short*)(ws + SIMB);            // [2][4096][2048]
    unsigned short* Kf = Qf + (size_t)2 * 4096 * 2048;            // [2][4096][2048]
    unsigned short* Vt = Kf + (size_t)2 * 4096 * 2048;            // [2][1024][4096]
    float*          sim1 = (float*)(ws + SIMB + (size_t)83886080); // after Vt
    float*          part = (float*)(ws + SIMB);                   // aliases Qf+Kf (dead after k2)
    const bool twoSim = ws_size >= (size_t)218103808;

    split_kernel<<<8192, 256, 0, stream>>>(x, Xhi, Xlo, 8192 * 1024 / 4);
    split_w_kernel<<<dim3(1024, 3), 256, 0, stream>>>(Wq, Wk, Wv, Whi, Wlo);
    proj_kernel<<<dim3(24, 64), 256, 0, stream>>>(Xhi, Xlo, Whi, Wlo,
                                                  bq, bk, bv, ph, Qf, Kf, Vt);

    const size_t sQK = (size_t)4096 * 2048;    // Qf/Kf batch stride (shorts)
    const size_t sV  = (size_t)1024 * 4096;    // Vt batch stride (shorts)
    const size_t sO  = (size_t)4096 * 1024;    // out / partial stride (floats)

    if (twoSim) {
        const size_t sSim = (size_t)(sim1 - sim0);   // floats between sims
        k2_gemm256<<<dim3(16, 16, 2), 512, 0, stream>>>(Qf, Kf, sim0, sQK, sQK, sSim);
        softmax_kernel<<<8192, 256, 0, stream>>>(sim0, sSim);
        // out partials: z = batch*2 + slice, each slice K=2048 of 4096
        k4_gemm256<<<dim3(4, 16, 4), 512, 0, stream>>>((const unsigned short*)sim0, Vt,
                                                       part, sSim * 2, sV, sO);
        reduce_kernel<<<8192, 256, 0, stream>>>(part, (float*)d_out);
    } else {
        hipMemsetAsync(d_out, 0, (size_t)2 * 4096 * 1024 * sizeof(float), stream);
        for (int b = 0; b < 2; b++) {
            const unsigned short* Qb = Qf + (size_t)b * sQK;
            const unsigned short* Kb = Kf + (size_t)b * sQK;
            const unsigned short* Vb = Vt + (size_t)b * sV;
            float* outb = (float*)d_out + (size_t)b * sO;
            k2_gemm256<<<dim3(16, 16, 1), 512, 0, stream>>>(Qb, Kb, sim0, 0, 0, 0);
            softmax_kernel<<<4096, 256, 0, stream>>>(sim0, 0);
            k4_gemm_atomic<<<dim3(8, 32, 4), 256, 0, stream>>>(
                (const unsigned short*)sim0, Vb, outb, 0, 0, 0);
        }
    }
}

// Round 5
// 503.900 us; speedup vs baseline: 1.0754x; 1.0079x over previous
//
#include <hip/hip_runtime.h>
#include <math.h>

// EulerAttention: B=2, S=4096, D=1024.
// Pipeline: [K0] split fp32 -> (hi,lo) bf16 for x and stacked W  (elementwise)
//           [K1] proj: 256x128-tile sub-phased pipelined split-bf16 GEMM,
//                3 phases/K-tile (hh/hl/lh), epilogue bias + HW-trig sincos
//                -> Qf/Kf bf16 features, V -> Vt
//           [K2] 256^2-tile sub-phased pipelined bf16 NT GEMM (z=2): sim = Qf@Kf^T
//           [K3] row softmax: fp32 sim -> bf16 P in place (row stride 8192)
//           [K4] same 256^2 core, split-K x2 -> separate fp32 partials
//           [K5] float4 reduce -> out
// ws (two-sim mode, 218MB): [sim0 67MB (aliases split bufs)][Qf 33.5][Kf 33.5]
//   [Vt 16.8][sim1 67]. Partials alias Qf+Kf after K2. Fallback <218MB:
//   sequential per-batch, atomic split-K k4 (old 128^2 core).
//
// Precision notes (load-bearing):
//  - sim ~ 640 +- ~15. sim MUST be fp32 (R1 failure).
//  - Q/K need near-fp32: inv_wl[0]~163 amplifies Q error. 3-term split-bf16.
//    fp32 accumulator -> term-major order within a K-tile is fine.
//  - libm sincosf -> scratch spill. Trig MUST be inline v_sin/v_cos.
// Perf notes:
//  - R11 stacked-K proj REGRESSED (233us: +45% L2 traffic, 2-stream K-stack
//    re-reads). This version stages all 4 streams once -> no extra traffic.
//  - R12 sub-phases on k2/k4: k2 212->~155us (~950 TF). XCD swizzle neutral.
//  - R13 proj bank-conflict fix: conflicts 2.5e7->0 but dur UNCHANGED (189us)
//    -> conflicts were hidden under the m97 barrier-drain stall. proj = 818 TF
//    = m97 plateau; structure, not conflicts, is the cap.
//  - R14 (this): proj -> sub-phased counted-vmcnt structure (the one that
//    helped k2): BM256xBN128, BK32, 3-deep 144KB LDS, 6 gload_lds/wave/K-tile,
//    3x16-MFMA phases, vmcnt(6) once/K-tile. Predicted ~165us.

typedef __attribute__((ext_vector_type(8))) short bf16x8;
typedef __attribute__((ext_vector_type(4))) float f32x4;

__device__ __forceinline__ float b2f(unsigned short h) {
    union { unsigned int u; float f; } v; v.u = ((unsigned int)h) << 16; return v.f;
}
__device__ __forceinline__ unsigned short f2b(float f) {
    union { float f; unsigned int u; } v; v.f = f;
    unsigned int r = v.u + 0x7fffu + ((v.u >> 16) & 1u);
    return (unsigned short)(r >> 16);
}

// Async global->LDS 16B per lane. LDS dest = wave-uniform base + lane*16.
__device__ __forceinline__ void async_load16(const unsigned short* g, unsigned short* l) {
    __builtin_amdgcn_global_load_lds(
        (const __attribute__((address_space(1))) unsigned int*)g,
        (__attribute__((address_space(3))) unsigned int*)l, 16, 0, 0);
}

// Branch-free sin/cos of th (radians). HW v_sin/v_cos take REVOLUTIONS.
__device__ __forceinline__ void fast_sincos(float th, float* sn, float* cs) {
    float rev = th * 0.15915494309189535f;
    float fr  = rev - floorf(rev);
    float s, c;
    asm("v_sin_f32 %0, %1" : "=v"(s) : "v"(fr));
    asm("v_cos_f32 %0, %1" : "=v"(c) : "v"(fr));
    *sn = s; *cs = c;
}

// ---------------- K0: fp32 -> (hi, lo) bf16 split ----------------
__global__ __launch_bounds__(256) void split_kernel(
    const float* __restrict__ src,
    unsigned short* __restrict__ hi, unsigned short* __restrict__ lo, int n4)
{
    int i = blockIdx.x * 256 + threadIdx.x;
    if (i >= n4) return;
    float4 v = ((const float4*)src)[i];
    float f[4] = { v.x, v.y, v.z, v.w };
    unsigned short h[4], l[4];
#pragma unroll
    for (int j = 0; j < 4; j++) {
        h[j] = f2b(f[j]);
        float r = f[j] - b2f(h[j]);
        l[j] = f2b(r);
    }
    uint2 ho, lv;
    ho.x = (unsigned int)h[0] | ((unsigned int)h[1] << 16);
    ho.y = (unsigned int)h[2] | ((unsigned int)h[3] << 16);
    lv.x = (unsigned int)l[0] | ((unsigned int)l[1] << 16);
    lv.y = (unsigned int)l[2] | ((unsigned int)l[3] << 16);
    ((uint2*)hi)[i] = ho;
    ((uint2*)lo)[i] = lv;
}

__global__ __launch_bounds__(256) void split_w_kernel(
    const float* __restrict__ Wq, const float* __restrict__ Wk,
    const float* __restrict__ Wv,
    unsigned short* __restrict__ hi, unsigned short* __restrict__ lo)
{
    const int y = blockIdx.y;
    const float* src = (y == 0) ? Wq : ((y == 1) ? Wk : Wv);
    size_t off4 = (size_t)y * (1024 * 1024 / 4);
    int i = blockIdx.x * 256 + threadIdx.x;
    float4 v = ((const float4*)src)[i];
    float f[4] = { v.x, v.y, v.z, v.w };
    unsigned short h[4], l[4];
#pragma unroll
    for (int j = 0; j < 4; j++) {
        h[j] = f2b(f[j]);
        float r = f[j] - b2f(h[j]);
        l[j] = f2b(r);
    }
    uint2 ho, lv;
    ho.x = (unsigned int)h[0] | ((unsigned int)h[1] << 16);
    ho.y = (unsigned int)h[2] | ((unsigned int)h[3] << 16);
    lv.x = (unsigned int)l[0] | ((unsigned int)l[1] << 16);
    lv.y = (unsigned int)l[2] | ((unsigned int)l[3] << 16);
    ((uint2*)hi)[off4 + i] = ho;
    ((uint2*)lo)[off4 + i] = lv;
}

// ---------------- K1: proj, sub-phased split-bf16 GEMM ----------------
// C[8192][3072]: 3-term split-bf16 (XhWh + XhWl + XlWh), K=1024, fp32 acc.
// 256x128 tile, BK=32, 8 waves (2 row-halves x 4 col-quarters), per-wave
// output 128x32 (acc[8][2]). LDS per K-tile (shorts):
//   Ah[0,8192) Al[8192,16384) Bh[16384,20480) Bl[20480,24576)  = 48KB
// 3-deep circular = 144KB -> 1 wg/CU, 8 waves. Staging: 48 1KB-chunks,
// 6 gload_lds per wave per K-tile (2 per phase), cgl-swizzled source,
// qx-swizzled b128 reads (verified zero-conflict layout).
// Per K-tile: 3 phases {ds_reads; stage 2 chunks; barrier; lgkmcnt(0);
// setprio(1); 16 MFMA; setprio(0); barrier}, vmcnt(6) once at phase 2 end.
// Phase terms: P0 ah*bh, P1 ah*bl, P2 al*bh. Grid (24,32)=768 = 3 CU-waves.
__global__ __launch_bounds__(512, 2) void proj_kernel(
    const unsigned short* __restrict__ Xhi, const unsigned short* __restrict__ Xlo,
    const unsigned short* __restrict__ Whi, const unsigned short* __restrict__ Wlo,
    const float* __restrict__ bq, const float* __restrict__ bk,
    const float* __restrict__ bv, const float* __restrict__ phase,
    unsigned short* __restrict__ Qf, unsigned short* __restrict__ Kf,
    unsigned short* __restrict__ Vt)
{
    const int m0 = blockIdx.y * 256;
    const int n0 = blockIdx.x * 128;

    __shared__ unsigned short lds[3 * 24576];   // 144 KiB

    const int tid  = threadIdx.x;           // 0..511
    const int lane = tid & 63;
    const int wid  = tid >> 6;              // 0..7
    const int wm   = wid >> 2;              // 0..1: 128-row half
    const int wn   = wid & 3;               // 0..3: 32-col quarter
    const int l15  = lane & 15, q = lane >> 4;
    const int lrow = lane >> 2;
    const int cgl  = (lane & 3) ^ ((lane >> 3) & 3);
    const int qx   = q ^ ((l15 >> 1) & 3);

    // Per-wave staging chunks: c = wid*6 + i, i=0..5. 48 chunks of 16 rows.
    const unsigned short* gsrc[6];
    int loff[6];
#pragma unroll
    for (int i = 0; i < 6; i++) {
        int c = wid * 6 + i;
        const unsigned short* sp; int row; int off;
        if (c < 16)      { sp = Xhi; row = m0 + c * 16;         off = c * 512; }
        else if (c < 32) { sp = Xlo; row = m0 + (c - 16) * 16;  off = 8192 + (c - 16) * 512; }
        else if (c < 40) { sp = Whi; row = n0 + (c - 32) * 16;  off = 16384 + (c - 32) * 512; }
        else             { sp = Wlo; row = n0 + (c - 40) * 16;  off = 20480 + (c - 40) * 512; }
        gsrc[i] = sp + (size_t)(row + lrow) * 1024 + cgl * 8;
        loff[i] = off;
    }

    f32x4 acc[8][2];
#pragma unroll
    for (int a = 0; a < 8; a++)
#pragma unroll
        for (int b = 0; b < 2; b++) acc[a][b] = (f32x4){0.f, 0.f, 0.f, 0.f};

    const int NT = 32;                      // K=1024 / BK=32

    auto STAGE2 = [&](int kt, int bufi, int i0) {
        unsigned short* buf = &lds[bufi * 24576];
#pragma unroll
        for (int j = 0; j < 2; j++)
            async_load16(gsrc[i0 + j] + kt * 32, &buf[loff[i0 + j]]);
    };

    // One K-tile: 3 barrier-paired 16-MFMA phases.
    // vm: 6 = steady-state counted wait, 0 = epilogue drain, -1 = none.
    auto ITER = [&](int t, int bc, int bs, bool doStage, int vm) {
        const unsigned short* buf = &lds[bc * 24576];
        bf16x8 ah[8], al[8], bh[2], bl[2];
        // ---- phase 0: hh ----
#pragma unroll
        for (int mt = 0; mt < 8; mt++)
            ah[mt] = *(const bf16x8*)&buf[((wm * 128 + mt * 16 + l15) * 4 + qx) * 8];
#pragma unroll
        for (int nt = 0; nt < 2; nt++)
            bh[nt] = *(const bf16x8*)&buf[16384 + ((wn * 32 + nt * 16 + l15) * 4 + qx) * 8];
        if (doStage) STAGE2(t + 2, bs, 0);
        asm volatile("s_barrier" ::: "memory");
        asm volatile("s_waitcnt lgkmcnt(0)" ::: "memory");
        __builtin_amdgcn_s_setprio(1);
#pragma unroll
        for (int mt = 0; mt < 8; mt++)
#pragma unroll
            for (int nt = 0; nt < 2; nt++)
                acc[mt][nt] = __builtin_amdgcn_mfma_f32_16x16x32_bf16(
                    ah[mt], bh[nt], acc[mt][nt], 0, 0, 0);
        __builtin_amdgcn_s_setprio(0);
        asm volatile("s_barrier" ::: "memory");
        // ---- phase 1: hl ----
#pragma unroll
        for (int nt = 0; nt < 2; nt++)
            bl[nt] = *(const bf16x8*)&buf[20480 + ((wn * 32 + nt * 16 + l15) * 4 + qx) * 8];
        if (doStage) STAGE2(t + 2, bs, 2);
        asm volatile("s_barrier" ::: "memory");
        asm volatile("s_waitcnt lgkmcnt(0)" ::: "memory");
        __builtin_amdgcn_s_setprio(1);
#pragma unroll
        for (int mt = 0; mt < 8; mt++)
#pragma unroll
            for (int nt = 0; nt < 2; nt++)
                acc[mt][nt] = __builtin_amdgcn_mfma_f32_16x16x32_bf16(
                    ah[mt], bl[nt], acc[mt][nt], 0, 0, 0);
        __builtin_amdgcn_s_setprio(0);
        asm volatile("s_barrier" ::: "memory");
        // ---- phase 2: lh ----
#pragma unroll
        for (int mt = 0; mt < 8; mt++)
            al[mt] = *(const bf16x8*)&buf[8192 + ((wm * 128 + mt * 16 + l15) * 4 + qx) * 8];
        if (doStage) STAGE2(t + 2, bs, 4);
        asm volatile("s_barrier" ::: "memory");
        asm volatile("s_waitcnt lgkmcnt(0)" ::: "memory");
        __builtin_amdgcn_s_setprio(1);
#pragma unroll
        for (int mt = 0; mt < 8; mt++)
#pragma unroll
            for (int nt = 0; nt < 2; nt++)
                acc[mt][nt] = __builtin_amdgcn_mfma_f32_16x16x32_bf16(
                    al[mt], bh[nt], acc[mt][nt], 0, 0, 0);
        __builtin_amdgcn_s_setprio(0);
        if (vm == 6)      asm volatile("s_waitcnt vmcnt(6)" ::: "memory");
        else if (vm == 0) asm volatile("s_waitcnt vmcnt(0)" ::: "memory");
        asm volatile("s_barrier" ::: "memory");
    };

    // Prologue: stage K-tiles 0,1 (12 loads/thread); ensure tile 0 landed.
    STAGE2(0, 0, 0); STAGE2(0, 0, 2); STAGE2(0, 0, 4);
    STAGE2(1, 1, 0); STAGE2(1, 1, 2); STAGE2(1, 1, 4);
    asm volatile("s_waitcnt vmcnt(6)" ::: "memory");
    asm volatile("s_barrier" ::: "memory");

    int bc = 0, bs = 2;
    for (int t = 0; t < NT - 2; ++t) {
        ITER(t, bc, bs, true, 6);
        bc = (bc == 2) ? 0 : bc + 1;
        bs = (bs == 2) ? 0 : bs + 1;
    }
    ITER(NT - 2, bc, 0, false, 0);
    bc = (bc == 2) ? 0 : bc + 1;
    ITER(NT - 1, bc, 0, false, -1);

    // ---- epilogue: bias + trig features / V transpose ----
    const int z = blockIdx.x >> 3;            // 0=Q, 1=K, 2=V (BN=128, 8/section)
    const float* bias = (z == 0) ? bq : ((z == 1) ? bk : bv);
    const float w0 = (float)(2.0 * M_PI / 1024.0);

#pragma unroll
    for (int nt = 0; nt < 2; nt++) {
        const int n  = n0 + wn * 32 + nt * 16 + l15;
        const int f  = n & 1023;
        const float bsv = bias[f];
        const float wl  = (float)(f + 1) * w0;
        const float inv = 1.0f / (wl + 1e-8f);
        const float phv = phase[f];
        unsigned short* dst = (z == 0) ? Qf : Kf;
#pragma unroll
        for (int mt = 0; mt < 8; mt++) {
#pragma unroll
            for (int r = 0; r < 4; r++) {
                const int m  = m0 + wm * 128 + mt * 16 + q * 4 + r;
                const int bb = m >> 12;
                const int s  = m & 4095;
                float val = acc[mt][nt][r] + bsv;
                if (z == 2) {
                    Vt[((size_t)bb * 1024 + f) * 4096 + s] = f2b(val);
                } else {
                    float th = fmaf(val, inv, phv);
                    float sn, cs;
                    fast_sincos(th, &sn, &cs);
                    size_t base = ((size_t)bb * 4096 + s) * 2048;
                    dst[base + f]        = f2b(cs);
                    dst[base + 1024 + f] = f2b(sn);
                }
            }
        }
    }
}

// ---------------- old 128^2 core: kept ONLY for atomic fallback ------------
template <int LDA, int LDB, int LDC, int KLEN, int SLICES, bool ATOMIC, bool PARTIAL>
__device__ __forceinline__ void gemm_core(
    const unsigned short* __restrict__ A,
    const unsigned short* __restrict__ Bm,
    float* __restrict__ C, size_t sA, size_t sB, size_t sC)
{
    const int bz = blockIdx.z;
    const int batch = bz / SLICES;
    const int slice = bz % SLICES;
    A  += (size_t)batch * sA;
    Bm += (size_t)batch * sB;
    C  += PARTIAL ? (size_t)bz * sC : (size_t)batch * sC;
    const int koff = slice * KLEN;

    const int m0 = blockIdx.y * 128;
    const int n0 = blockIdx.x * 128;

    __shared__ unsigned short As[128 * 32];
    __shared__ unsigned short Bs[128 * 32];

    const int tid  = threadIdx.x;
    const int lane = tid & 63;
    const int w    = tid >> 6;
    const int wr   = w >> 1, wc = w & 1;
    const int l15  = lane & 15, q = lane >> 4;
    const int lrow = lane >> 2;
    const int cgl  = (lane & 3) ^ ((lane >> 3) & 3);
    const int qx   = q ^ ((l15 >> 1) & 3);

    f32x4 acc[4][4];
#pragma unroll
    for (int a = 0; a < 4; a++)
#pragma unroll
        for (int b = 0; b < 4; b++) acc[a][b] = (f32x4){0.f, 0.f, 0.f, 0.f};

    for (int k0 = 0; k0 < KLEN; k0 += 32) {
        int kg = koff + k0;
#pragma unroll
        for (int i = 0; i < 2; i++) {
            int chunk = w * 2 + i;
            async_load16(&A[(size_t)(m0 + chunk * 16 + lrow) * LDA + kg + cgl * 8],
                         &As[chunk * 512]);
            async_load16(&Bm[(size_t)(n0 + chunk * 16 + lrow) * LDB + kg + cgl * 8],
                         &Bs[chunk * 512]);
        }
        __syncthreads();
        bf16x8 af[4], bfr[4];
#pragma unroll
        for (int mt = 0; mt < 4; mt++) {
            int ar = wr * 64 + mt * 16 + l15;
            af[mt] = *(const bf16x8*)&As[(ar * 4 + qx) * 8];
        }
#pragma unroll
        for (int nt = 0; nt < 4; nt++) {
            int br = wc * 64 + nt * 16 + l15;
            bfr[nt] = *(const bf16x8*)&Bs[(br * 4 + qx) * 8];
        }
#pragma unroll
        for (int mt = 0; mt < 4; mt++)
#pragma unroll
            for (int nt = 0; nt < 4; nt++)
                acc[mt][nt] = __builtin_amdgcn_mfma_f32_16x16x32_bf16(
                    af[mt], bfr[nt], acc[mt][nt], 0, 0, 0);
        __syncthreads();
    }

#pragma unroll
    for (int mt = 0; mt < 4; mt++) {
#pragma unroll
        for (int nt = 0; nt < 4; nt++) {
            int n = n0 + wc * 64 + nt * 16 + l15;
#pragma unroll
            for (int r = 0; r < 4; r++) {
                int m = m0 + wr * 64 + mt * 16 + q * 4 + r;
                float* p = &C[(size_t)m * LDC + n];
                if (ATOMIC)
                    __hip_atomic_fetch_add(p, acc[mt][nt][r],
                                           __ATOMIC_RELAXED, __HIP_MEMORY_SCOPE_AGENT);
                else
                    *p = acc[mt][nt][r];
            }
        }
    }
}

// k4 fallback path (one sim): atomic split-K x4 within one batch.
__global__ __launch_bounds__(256) void k4_gemm_atomic(
    const unsigned short* __restrict__ A, const unsigned short* __restrict__ Bm,
    float* __restrict__ C, size_t sA, size_t sB, size_t sC)
{
    gemm_core<8192, 4096, 1024, 1024, 4, true, false>(A, Bm, C, sA, sB, sC);
}

// ---------------- 256^2 sub-phased pipelined core (m201-style) -------------
// 512 threads = 8 waves (2 row-halves x 4 col-quarters), per-wave C = 128x64
// (acc[8][4]), BK=32, mfma_f32_16x16x32_bf16.
// LDS: 4-deep circular K-tile buffers; counted vmcnt(8), never drained in
// main loop; bijective XCD-chunked block swizzle (neutral, kept).
template <int GX, int LDA, int LDB, int LDC, int KLEN, int SLICES, bool PARTIAL>
__device__ __forceinline__ void gemm256_core(
    const unsigned short* __restrict__ A,
    const unsigned short* __restrict__ Bm,
    float* __restrict__ C, size_t sA, size_t sB, size_t sC)
{
    const int bz = blockIdx.z;
    const int batch = bz / SLICES;
    const int slice = bz % SLICES;
    A  += (size_t)batch * sA;
    Bm += (size_t)batch * sB;
    C  += PARTIAL ? (size_t)bz * sC : (size_t)batch * sC;
    const int koff = slice * KLEN;

    const int nwg = GX * 16;
    const int lin = blockIdx.x + GX * blockIdx.y;
    const int nb  = (lin & 7) * (nwg >> 3) + (lin >> 3);
    const int m0 = (nb / GX) * 256;
    const int n0 = (nb % GX) * 256;

    __shared__ unsigned short lds[4 * 16384];   // 128 KiB

    const int tid  = threadIdx.x;           // 0..511
    const int lane = tid & 63;
    const int wid  = tid >> 6;              // 0..7
    const int wm   = wid >> 2;              // 0..1: 128-row half
    const int wn   = wid & 3;               // 0..3: 64-col quarter
    const int l15  = lane & 15, q = lane >> 4;
    const int lrow = lane >> 2;
    const int cgl  = (lane & 3) ^ ((lane >> 3) & 3);
    const int qx   = q ^ ((l15 >> 1) & 3);

    f32x4 acc[8][4];
#pragma unroll
    for (int a = 0; a < 8; a++)
#pragma unroll
        for (int b = 0; b < 4; b++) acc[a][b] = (f32x4){0.f, 0.f, 0.f, 0.f};

    const int NT = KLEN / 32;               // 64 K-tiles

    const int c0 = (wid * 2 + 0) * 512;
    const int c1 = (wid * 2 + 1) * 512;
    const unsigned short* aS0 = &A[(size_t)(m0 + (wid * 2 + 0) * 16 + lrow) * LDA + koff + cgl * 8];
    const unsigned short* aS1 = &A[(size_t)(m0 + (wid * 2 + 1) * 16 + lrow) * LDA + koff + cgl * 8];
    const unsigned short* bS0 = &Bm[(size_t)(n0 + (wid * 2 + 0) * 16 + lrow) * LDB + koff + cgl * 8];
    const unsigned short* bS1 = &Bm[(size_t)(n0 + (wid * 2 + 1) * 16 + lrow) * LDB + koff + cgl * 8];

    auto STAGE_A = [&](int kt) {
        unsigned short* buf = &lds[(kt & 3) * 16384];
        async_load16(aS0 + (size_t)kt * 32, &buf[c0]);
        async_load16(aS1 + (size_t)kt * 32, &buf[c1]);
    };
    auto STAGE_B = [&](int kt) {
        unsigned short* buf = &lds[(kt & 3) * 16384];
        async_load16(bS0 + (size_t)kt * 32, &buf[8192 + c0]);
        async_load16(bS1 + (size_t)kt * 32, &buf[8192 + c1]);
    };

    auto ITER = [&](int t, bool doStage, int vm) {
        const unsigned short* buf = &lds[(t & 3) * 16384];
        bf16x8 af[8], bfr[4];
        // ---- sub-phase A ----
#pragma unroll
        for (int mt = 0; mt < 8; mt++)
            af[mt] = *(const bf16x8*)&buf[((wm * 128 + mt * 16 + l15) * 4 + qx) * 8];
#pragma unroll
        for (int nt = 0; nt < 2; nt++)
            bfr[nt] = *(const bf16x8*)&buf[8192 + ((wn * 64 + nt * 16 + l15) * 4 + qx) * 8];
        if (doStage) STAGE_A(t + 3);
        asm volatile("s_barrier" ::: "memory");
        asm volatile("s_waitcnt lgkmcnt(0)" ::: "memory");
        __builtin_amdgcn_s_setprio(1);
#pragma unroll
        for (int mt = 0; mt < 8; mt++)
#pragma unroll
            for (int nt = 0; nt < 2; nt++)
                acc[mt][nt] = __builtin_amdgcn_mfma_f32_16x16x32_bf16(
                    af[mt], bfr[nt], acc[mt][nt], 0, 0, 0);
        __builtin_amdgcn_s_setprio(0);
        asm volatile("s_barrier" ::: "memory");
        // ---- sub-phase B ----
#pragma unroll
        for (int nt = 2; nt < 4; nt++)
            bfr[nt] = *(const bf16x8*)&buf[8192 + ((wn * 64 + nt * 16 + l15) * 4 + qx) * 8];
        if (doStage) STAGE_B(t + 3);
        asm volatile("s_barrier" ::: "memory");
        asm volatile("s_waitcnt lgkmcnt(0)" ::: "memory");
        __builtin_amdgcn_s_setprio(1);
#pragma unroll
        for (int mt = 0; mt < 8; mt++)
#pragma unroll
            for (int nt = 2; nt < 4; nt++)
                acc[mt][nt] = __builtin_amdgcn_mfma_f32_16x16x32_bf16(
                    af[mt], bfr[nt], acc[mt][nt], 0, 0, 0);
        __builtin_amdgcn_s_setprio(0);
        if (vm == 8)      asm volatile("s_waitcnt vmcnt(8)" ::: "memory");
        else if (vm == 4) asm volatile("s_waitcnt vmcnt(4)" ::: "memory");
        else if (vm == 0) asm volatile("s_waitcnt vmcnt(0)" ::: "memory");
        asm volatile("s_barrier" ::: "memory");
    };

    STAGE_A(0); STAGE_B(0);
    STAGE_A(1); STAGE_B(1);
    STAGE_A(2); STAGE_B(2);
    asm volatile("s_waitcnt vmcnt(8)" ::: "memory");
    asm volatile("s_barrier" ::: "memory");

    for (int t = 0; t < NT - 3; ++t)
        ITER(t, true, 8);
    ITER(NT - 3, false, 4);
    ITER(NT - 2, false, 0);
    ITER(NT - 1, false, -1);

#pragma unroll
    for (int mt = 0; mt < 8; mt++) {
#pragma unroll
        for (int nt = 0; nt < 4; nt++) {
            const int n = n0 + wn * 64 + nt * 16 + l15;
#pragma unroll
            for (int r = 0; r < 4; r++) {
                const int m = m0 + wm * 128 + mt * 16 + q * 4 + r;
                C[(size_t)m * LDC + n] = acc[mt][nt][r];
            }
        }
    }
}

__global__ __launch_bounds__(512, 2) void k2_gemm256(
    const unsigned short* __restrict__ A, const unsigned short* __restrict__ Bm,
    float* __restrict__ C, size_t sA, size_t sB, size_t sC)
{
    gemm256_core<16, 2048, 2048, 4096, 2048, 1, false>(A, Bm, C, sA, sB, sC);
}

__global__ __launch_bounds__(512, 2) void k4_gemm256(
    const unsigned short* __restrict__ A, const unsigned short* __restrict__ Bm,
    float* __restrict__ C, size_t sA, size_t sB, size_t sC)
{
    gemm256_core<4, 8192, 4096, 1024, 2048, 2, true>(A, Bm, C, sA, sB, sC);
}

// ---------------- K5: reduce partials -> out ----------------
__global__ __launch_bounds__(256) void reduce_kernel(
    const float* __restrict__ part, float* __restrict__ out)
{
    int j4 = blockIdx.x * 256 + threadIdx.x;      // float4 index, < 2*1048576
    int b  = j4 >> 20;
    int jj = j4 & 1048575;
    const float4* p0 = (const float4*)(part + (size_t)(b * 2 + 0) * 4194304);
    const float4* p1 = (const float4*)(part + (size_t)(b * 2 + 1) * 4194304);
    float4 a = p0[jj], c = p1[jj];
    float4 r; r.x = a.x + c.x; r.y = a.y + c.y; r.z = a.z + c.z; r.w = a.w + c.w;
    ((float4*)out)[j4] = r;
}

// ---------------- K3: row softmax, fp32 sim -> bf16 P in place -------------
__global__ __launch_bounds__(256) void softmax_kernel(float* __restrict__ simbase,
                                                      size_t batchStride)
{
    const int row = blockIdx.x;
    float* sim = simbase + (size_t)(row >> 12) * batchStride;
    const int r = row & 4095;
    const float* pin = sim + (size_t)r * 4096;
    unsigned short* pout = (unsigned short*)sim + (size_t)r * 8192;
    const int tid = threadIdx.x;

    float v[16];
#pragma unroll
    for (int i = 0; i < 4; i++) {
        float4 d = ((const float4*)pin)[tid * 4 + i];
        v[4 * i + 0] = d.x * 0.03125f;
        v[4 * i + 1] = d.y * 0.03125f;
        v[4 * i + 2] = d.z * 0.03125f;
        v[4 * i + 3] = d.w * 0.03125f;
    }

    float m = v[0];
#pragma unroll
    for (int i = 1; i < 16; i++) m = fmaxf(m, v[i]);
    for (int o = 32; o > 0; o >>= 1) m = fmaxf(m, __shfl_xor(m, o));
    __shared__ float red[4];
    if ((tid & 63) == 0) red[tid >> 6] = m;
    __syncthreads();
    m = fmaxf(fmaxf(red[0], red[1]), fmaxf(red[2], red[3]));
    __syncthreads();

    float e[16];
    float s = 0.f;
#pragma unroll
    for (int i = 0; i < 16; i++) { e[i] = expf(v[i] - m); s += e[i]; }
    for (int o = 32; o > 0; o >>= 1) s += __shfl_xor(s, o);
    if ((tid & 63) == 0) red[tid >> 6] = s;
    __syncthreads();
    float l = (red[0] + red[1]) + (red[2] + red[3]);
    float inv = 1.0f / l;

#pragma unroll
    for (int c = 0; c < 2; c++) {
        unsigned int wds[4];
#pragma unroll
        for (int i = 0; i < 4; i++) {
            unsigned int lo = f2b(e[c * 8 + 2 * i] * inv);
            unsigned int hi = f2b(e[c * 8 + 2 * i + 1] * inv);
            wds[i] = lo | (hi << 16);
        }
        uint4 o4; o4.x = wds[0]; o4.y = wds[1]; o4.z = wds[2]; o4.w = wds[3];
        ((uint4*)pout)[tid * 2 + c] = o4;
    }
}

extern "C" void kernel_launch(void* const* d_in, const int* in_sizes, int n_in,
                              void* d_out, int out_size, void* d_ws, size_t ws_size,
                              hipStream_t stream)
{
    const float* x  = (const float*)d_in[0];
    const float* Wq = (const float*)d_in[1];
    const float* bq = (const float*)d_in[2];
    const float* Wk = (const float*)d_in[3];
    const float* bk = (const float*)d_in[4];
    const float* Wv = (const float*)d_in[5];
    const float* bv = (const float*)d_in[6];
    const float* ph = (const float*)d_in[7];

    char* ws = (char*)d_ws;
    const size_t SIMB = (size_t)4096 * 4096 * 4;                  // 67.1MB
    unsigned short* Xhi = (unsigned short*)ws;                    // aliases sim0
    unsigned short* Xlo = Xhi + (size_t)8192 * 1024;
    unsigned short* Whi = Xlo + (size_t)8192 * 1024;
    unsigned short* Wlo = Whi + (size_t)3072 * 1024;
    float*          sim0 = (float*)ws;
    unsigned short* Qf = (unsigned short*)(ws + SIMB);            // [2][4096][2048]
    unsigned short* Kf = Qf + (size_t)2 * 4096 * 2048;            // [2][4096][2048]
    unsigned short* Vt = Kf + (size_t)2 * 4096 * 2048;            // [2][1024][4096]
    float*          sim1 = (float*)(ws + SIMB + (size_t)83886080); // after Vt
    float*          part = (float*)(ws + SIMB);                   // aliases Qf+Kf (dead after k2)
    const bool twoSim = ws_size >= (size_t)218103808;

    split_kernel<<<8192, 256, 0, stream>>>(x, Xhi, Xlo, 8192 * 1024 / 4);
    split_w_kernel<<<dim3(1024, 3), 256, 0, stream>>>(Wq, Wk, Wv, Whi, Wlo);
    proj_kernel<<<dim3(24, 32), 512, 0, stream>>>(Xhi, Xlo, Whi, Wlo,
                                                  bq, bk, bv, ph, Qf, Kf, Vt);

    const size_t sQK = (size_t)4096 * 2048;    // Qf/Kf batch stride (shorts)
    const size_t sV  = (size_t)1024 * 4096;    // Vt batch stride (shorts)
    const size_t sO  = (size_t)4096 * 1024;    // out / partial stride (floats)

    if (twoSim) {
        const size_t sSim = (size_t)(sim1 - sim0);   // floats between sims
        k2_gemm256<<<dim3(16, 16, 2), 512, 0, stream>>>(Qf, Kf, sim0, sQK, sQK, sSim);
        softmax_kernel<<<8192, 256, 0, stream>>>(sim0, sSim);
        // out partials: z = batch*2 + slice, each slice K=2048 of 4096
        k4_gemm256<<<dim3(4, 16, 4), 512, 0, stream>>>((const unsigned short*)sim0, Vt,
                                                       part, sSim * 2, sV, sO);
        reduce_kernel<<<8192, 256, 0, stream>>>(part, (float*)d_out);
    } else {
        hipMemsetAsync(d_out, 0, (size_t)2 * 4096 * 1024 * sizeof(float), stream);
        for (int b = 0; b < 2; b++) {
            const unsigned short* Qb = Qf + (size_t)b * sQK;
            const unsigned short* Kb = Kf + (size_t)b * sQK;
            const unsigned short* Vb = Vt + (size_t)b * sV;
            float* outb = (float*)d_out + (size_t)b * sO;
            k2_gemm256<<<dim3(16, 16, 1), 512, 0, stream>>>(Qb, Kb, sim0, 0, 0, 0);
            softmax_kernel<<<4096, 256, 0, stream>>>(sim0, 0);
            k4_gemm_atomic<<<dim3(8, 32, 4), 256, 0, stream>>>(
                (const unsigned short*)sim0, Vb, outb, 0, 0, 0);
        }
    }
}